// Round 3
// baseline (973.580 us; speedup 1.0000x reference)
//
#include <hip/hip_runtime.h>
#include <hip/hip_bf16.h>
#include <stdint.h>

typedef unsigned short u16;
typedef __attribute__((ext_vector_type(8))) short short8;
typedef __attribute__((ext_vector_type(4))) float f32x4;

#define NB 64
#define NN 4096
#define NS 8
#define ND 256
#define NSEG 64          // per-wave output sub-segments (64 n each)
#define GROWS (NB*NN)   // 262144

__device__ inline u16 f2bf(float f) {
    uint32_t u = __float_as_uint(f);
    u = (u + 0x7FFFu + ((u >> 16) & 1u)) >> 16;
    return (u16)u;
}
__device__ inline float bf2f(u16 h) {
    return __uint_as_float(((uint32_t)h) << 16);
}
__device__ inline f32x4 mfma16(short8 a, short8 b, f32x4 c) {
    return __builtin_amdgcn_mfma_f32_16x16x32_bf16(a, b, c, 0, 0, 0);
}
__device__ inline void gload_lds16(const u16* g, u16* l) {
    __builtin_amdgcn_global_load_lds(
        (const __attribute__((address_space(1))) void*)g,
        (__attribute__((address_space(3))) void*)l,
        16, 0, 0);
}

// ---------------- weight conversion fp32 -> bf16 (once per launch) ----------
__global__ __launch_bounds__(256) void prep_w(
        const float* __restrict__ wk, const float* __restrict__ wv, const float* __restrict__ wq,
        const float* __restrict__ wih, const float* __restrict__ whh,
        const float* __restrict__ w1, const float* __restrict__ w2,
        u16* __restrict__ wkvb, u16* __restrict__ wqb, u16* __restrict__ wihb,
        u16* __restrict__ whhb, u16* __restrict__ w1b, u16* __restrict__ w2b) {
    int i = blockIdx.x * 256 + threadIdx.x;
    if (i < 131072) { wkvb[i] = f2bf(i < 65536 ? wk[i] : wv[i - 65536]); return; }
    i -= 131072;
    if (i < 65536) { wqb[i] = f2bf(wq[i]); return; }
    i -= 65536;
    if (i < 196608) { wihb[i] = f2bf(wih[i]); return; }
    i -= 196608;
    if (i < 196608) { whhb[i] = f2bf(whh[i]); return; }
    i -= 196608;
    if (i < 65536) { w1b[i] = f2bf(w1[i]); return; }
    i -= 65536;
    w2b[i] = f2bf(w2[i]);
}

// ---------------- streaming LN + cast: inputs fp32 -> xb bf16 ---------------
__global__ __launch_bounds__(256) void ln_cast(
        const float* __restrict__ inp, const float* __restrict__ g,
        const float* __restrict__ bt, u16* __restrict__ xb) {
    const int tid = threadIdx.x, wid = tid >> 6, lane = tid & 63;
    const long r0 = (long)blockIdx.x * 64 + wid * 16;
    float4 g4 = reinterpret_cast<const float4*>(g)[lane];
    float4 b4 = reinterpret_cast<const float4*>(bt)[lane];
#pragma unroll 4
    for (int i = 0; i < 16; i++) {
        long row = r0 + i;
        float4 v = reinterpret_cast<const float4*>(inp + row*256)[lane];
        float s = v.x + v.y + v.z + v.w;
        float ss = v.x*v.x + v.y*v.y + v.z*v.z + v.w*v.w;
#pragma unroll
        for (int off = 32; off >= 1; off >>= 1) { s += __shfl_xor(s, off, 64); ss += __shfl_xor(ss, off, 64); }
        float mean = s * (1.0f/256.0f);
        float rstd = rsqrtf(ss * (1.0f/256.0f) - mean*mean + 1e-5f);
        ushort4 o;
        o.x = f2bf((v.x-mean)*rstd*g4.x + b4.x);
        o.y = f2bf((v.y-mean)*rstd*g4.y + b4.y);
        o.z = f2bf((v.z-mean)*rstd*g4.z + b4.z);
        o.w = f2bf((v.w-mean)*rstd*g4.w + b4.w);
        reinterpret_cast<ushort4*>(xb + row*256)[lane] = o;
    }
}

// ---------------- K/V projection GEMM from bf16 xb --------------------------
// A staged via async global_load_lds into linear LDS (chunk-XOR swizzle on the
// per-lane GLOBAL source). W fragments preloaded one ct ahead so the epilogue
// covers the L2 latency. k written in-place over xb.
__global__ __launch_bounds__(256) void gemm_kv(
        u16* kx, const u16* __restrict__ W,
        const float* __restrict__ bk, const float* __restrict__ bv,
        u16* __restrict__ vT) {
    __shared__ u16 A[64*256];           // 32768 B, linear, swizzled content
    __shared__ u16 ctw[4][64*36];       // 18432 B per-wave epilogue buffers
    const int blk = blockIdx.x;
    const long r0 = (long)blk * 64;
    const int tid = threadIdx.x, wid = tid >> 6, lane = tid & 63;
    const int l15 = lane & 15, quad = lane >> 4, kq = quad * 8;
    const int sw = l15 & 7;

    // stage 16 rows per wave: 8 x global_load_lds, 2 rows (1KB) per instr.
    // LDS[r][chunk c] holds global chunk (c ^ (r&7)) of row r.
    {
        const int rb = wid * 16;
        const int half = lane >> 5, c = lane & 31;
#pragma unroll
        for (int i = 0; i < 8; i++) {
            const int r = rb + i*2 + half;
            const int cg = c ^ (r & 7);
            gload_lds16(kx + (r0 + r)*256 + cg*8, &A[(rb + i*2)*256]);
        }
    }

    short8 wf0[8], wf1[8];
    const u16* Wbase = &W[(size_t)(wid*32 + l15)*256 + kq];
    // preload ct=0's W fragments BEFORE the barrier: they drain with vmcnt(0)
#pragma unroll
    for (int kk = 0; kk < 8; kk++) {
        wf0[kk] = *reinterpret_cast<const short8*>(&Wbase[kk*32]);
        wf1[kk] = *reinterpret_cast<const short8*>(&Wbase[16*256 + kk*32]);
    }
    __syncthreads();   // drains vmcnt: all staging (and W) landed

    const long bb = r0 >> 12;
    const long nb0 = r0 & 4095;
    for (int ct = 0; ct < 4; ct++) {
        const int o0 = ct * 128;
        f32x4 acc[4][2];
#pragma unroll
        for (int rt = 0; rt < 4; rt++) { acc[rt][0] = (f32x4){0.f,0.f,0.f,0.f}; acc[rt][1] = (f32x4){0.f,0.f,0.f,0.f}; }
#pragma unroll
        for (int kk = 0; kk < 8; kk++) {
#pragma unroll
            for (int rt = 0; rt < 4; rt++) {
                short8 af = *reinterpret_cast<const short8*>(
                    &A[(rt*16 + l15)*256 + (((kk*4 + quad) ^ sw) * 8)]);
                acc[rt][0] = mfma16(af, wf0[kk], acc[rt][0]);
                acc[rt][1] = mfma16(af, wf1[kk], acc[rt][1]);
            }
        }
        // issue next ct's W loads now; the epilogue below covers their latency
        if (ct < 3) {
            const u16* Wn = Wbase + (size_t)(ct+1)*128*256;
#pragma unroll
            for (int kk = 0; kk < 8; kk++) {
                wf0[kk] = *reinterpret_cast<const short8*>(&Wn[kk*32]);
                wf1[kk] = *reinterpret_cast<const short8*>(&Wn[16*256 + kk*32]);
            }
        }
        if (ct < 2) {
            // k half: per-wave transpose buffer [64][36], then 64B-chunk stores (in-place over xb)
            float bb0 = bk[o0 + wid*32 + l15], bb1 = bk[o0 + wid*32 + 16 + l15];
            u16* C = ctw[wid];
#pragma unroll
            for (int rt = 0; rt < 4; rt++) {
                int m = rt*16 + quad*4;
#pragma unroll
                for (int r = 0; r < 4; r++) {
                    C[(m+r)*36 + l15]      = f2bf(acc[rt][0][r] + bb0);
                    C[(m+r)*36 + 16 + l15] = f2bf(acc[rt][1][r] + bb1);
                }
            }
#pragma unroll
            for (int it = 0; it < 4; it++) {
                int m = it*16 + (lane >> 2);
                short8 val = *reinterpret_cast<const short8*>(&C[m*36 + (lane & 3)*8]);
                *reinterpret_cast<short8*>(&kx[(r0 + m)*256 + o0 + wid*32 + (lane & 3)*8]) = val;
            }
        } else {
            // v half: transposed to vT[b][d][n]; per-wave [32][72] buffer
            float bb0 = bv[(o0-256) + wid*32 + l15], bb1 = bv[(o0-256) + wid*32 + 16 + l15];
            u16* C = ctw[wid];
#pragma unroll
            for (int rt = 0; rt < 4; rt++) {
                int m = rt*16 + quad*4;
                ushort4 p0, p1;
                p0.x = f2bf(acc[rt][0][0] + bb0); p0.y = f2bf(acc[rt][0][1] + bb0);
                p0.z = f2bf(acc[rt][0][2] + bb0); p0.w = f2bf(acc[rt][0][3] + bb0);
                p1.x = f2bf(acc[rt][1][0] + bb1); p1.y = f2bf(acc[rt][1][1] + bb1);
                p1.z = f2bf(acc[rt][1][2] + bb1); p1.w = f2bf(acc[rt][1][3] + bb1);
                *reinterpret_cast<ushort4*>(&C[(l15)*72 + m])      = p0;
                *reinterpret_cast<ushort4*>(&C[(16 + l15)*72 + m]) = p1;
            }
#pragma unroll
            for (int it = 0; it < 4; it++) {
                int lc = it*8 + (lane >> 3);
                short8 val = *reinterpret_cast<const short8*>(&C[lc*72 + (lane & 7)*8]);
                long d = (o0 - 256) + wid*32 + lc;
                *reinterpret_cast<short8*>(&vT[(bb*256 + d)*4096 + nb0 + (lane & 7)*8]) = val;
            }
        }
        // ctw is per-wave and DS ops are in-order per wave: no barrier needed
    }
}

// ---------------- q projection (iteration 0 only) ---------------------------
__global__ __launch_bounds__(256) void q_proj(
        const float* __restrict__ slots, const u16* __restrict__ wqb,
        const float* __restrict__ bq, const float* __restrict__ gs, const float* __restrict__ bs,
        u16* __restrict__ qb) {
    __shared__ u16 sn[16*264];
    const int b = blockIdx.x;
    const int tid = threadIdx.x, wid = tid >> 6, lane = tid & 63;
    const int l15 = lane & 15, kq = (lane >> 4) * 8;
    for (int rr = wid; rr < 8; rr += 4) {
        float4 v = reinterpret_cast<const float4*>(slots + (size_t)(b*8 + rr)*256)[lane];
        float s = v.x + v.y + v.z + v.w;
        float ss = v.x*v.x + v.y*v.y + v.z*v.z + v.w*v.w;
#pragma unroll
        for (int off = 32; off >= 1; off >>= 1) { s += __shfl_xor(s, off, 64); ss += __shfl_xor(ss, off, 64); }
        float mean = s * (1.f/256.f);
        float rstd = rsqrtf(ss * (1.f/256.f) - mean*mean + 1e-5f);
        float4 g4 = reinterpret_cast<const float4*>(gs)[lane];
        float4 b4 = reinterpret_cast<const float4*>(bs)[lane];
        ushort4 o;
        o.x = f2bf((v.x-mean)*rstd*g4.x + b4.x);
        o.y = f2bf((v.y-mean)*rstd*g4.y + b4.y);
        o.z = f2bf((v.z-mean)*rstd*g4.z + b4.z);
        o.w = f2bf((v.w-mean)*rstd*g4.w + b4.w);
        *reinterpret_cast<ushort4*>(&sn[rr*264 + lane*4]) = o;
    }
    {
        ushort4 z = {0,0,0,0};
        for (int rr = 8 + wid; rr < 16; rr += 4)
            *reinterpret_cast<ushort4*>(&sn[rr*264 + lane*4]) = z;
    }
    __syncthreads();
    short8 af[8];
#pragma unroll
    for (int k = 0; k < 8; k++) af[k] = *reinterpret_cast<const short8*>(&sn[l15*264 + k*32 + kq]);
#pragma unroll
    for (int ct = 0; ct < 4; ct++) {
        int o0 = (wid*4 + ct)*16;
        f32x4 a = (f32x4){0.f,0.f,0.f,0.f};
#pragma unroll
        for (int k = 0; k < 8; k++) {
            short8 bw = *reinterpret_cast<const short8*>(&wqb[(size_t)(o0 + l15)*256 + k*32 + kq]);
            a = mfma16(af[k], bw, a);
        }
        if (lane < 32) {
            int sb = (lane >> 4)*4;
            float bb = bq[o0 + l15];
#pragma unroll
            for (int r = 0; r < 4; r++)
                qb[(size_t)(b*8 + sb + r)*256 + o0 + l15] = f2bf(a[r] + bb);
        }
    }
}

// ---------------- fused attention pass: fully wave-autonomous ---------------
// 1024 blocks x 4 waves; wave owns a 64-n strip AND its own output slice
// num_part[b][seg64][8][256] -> no cross-wave reduction, no barrier, tiny LDS.
__global__ __launch_bounds__(256) void attn(
        const u16* __restrict__ qb, const u16* __restrict__ kb,
        const u16* __restrict__ vT, float* __restrict__ num_part, float* __restrict__ den_part) {
    __shared__ u16 pb_all[4][16*72];
    const int b = blockIdx.x >> 4;
    const int seg = blockIdx.x & 15;
    const int tid = threadIdx.x, wid = tid >> 6, lane = tid & 63;
    const int l15 = lane & 15, quad = lane >> 4, kq = quad * 8;
    const int seg64 = seg*4 + wid;            // this wave's output sub-segment
    u16* pb = pb_all[wid];
    {   // zero P pad rows 8..15 of own wave's buffer
        short8 z = {0,0,0,0,0,0,0,0};
        int r8 = 8 + (lane >> 3), c8 = (lane & 7)*8;
        *reinterpret_cast<short8*>(&pb[r8*72 + c8]) = z;
    }
    // q A-fragment direct from global, rows >=8 zeroed
    short8 aq[8];
    {
        const u16* qrow = &qb[((size_t)b*8 + (l15 & 7))*256 + kq];
        short8 z = {0,0,0,0,0,0,0,0};
#pragma unroll
        for (int kk = 0; kk < 8; kk++) {
            short8 t = *reinterpret_cast<const short8*>(&qrow[kk*32]);
            aq[kk] = (l15 < 8) ? t : z;
        }
    }
    const int n_w = seg64 * 64;
    const u16* kbase = &kb[((size_t)b*4096 + n_w + l15)*256 + kq];
    const u16* vbase = &vT[((size_t)b*256 + l15)*4096 + n_w + kq];
    f32x4 acc[16];
#pragma unroll
    for (int dt = 0; dt < 16; dt++) acc[dt] = (f32x4){0.f,0.f,0.f,0.f};
    float psum[4] = {0.f,0.f,0.f,0.f};
    short8 kf[8];
#pragma unroll
    for (int kk = 0; kk < 8; kk++) kf[kk] = *reinterpret_cast<const short8*>(&kbase[kk*32]);

    f32x4 dots[4];
#pragma unroll
    for (int nt = 0; nt < 4; nt++) {
        short8 kn[8];
        if (nt < 3) {
            const u16* kp = kbase + (size_t)((nt+1)*16)*256;
#pragma unroll
            for (int kk = 0; kk < 8; kk++) kn[kk] = *reinterpret_cast<const short8*>(&kp[kk*32]);
        }
        f32x4 d = (f32x4){0.f,0.f,0.f,0.f};
#pragma unroll
        for (int kk = 0; kk < 8; kk++) d = mfma16(aq[kk], kf[kk], d);
        dots[nt] = d;
        if (nt < 3) {
#pragma unroll
            for (int kk = 0; kk < 8; kk++) kf[kk] = kn[kk];
        }
    }
    // issue first two V d-tiles now: they fly during the softmax VALU phase
    short8 v0[2], v1[2];
    {
        v0[0] = *reinterpret_cast<const short8*>(vbase);
        v1[0] = *reinterpret_cast<const short8*>(vbase + 32);
        const u16* vr2 = vbase + (size_t)16*4096;
        v0[1] = *reinterpret_cast<const short8*>(vr2);
        v1[1] = *reinterpret_cast<const short8*>(vr2 + 32);
    }
#pragma unroll
    for (int nt = 0; nt < 4; nt++) {
        float t0 = dots[nt][0]*0.0625f, t1 = dots[nt][1]*0.0625f;
        float t2 = dots[nt][2]*0.0625f, t3 = dots[nt][3]*0.0625f;
        float m4 = fmaxf(fmaxf(t0,t1), fmaxf(t2,t3));
        float m8 = fmaxf(m4, __shfl_xor(m4, 16, 64));
        float e0 = __expf(t0-m8), e1 = __expf(t1-m8), e2 = __expf(t2-m8), e3 = __expf(t3-m8);
        float s4 = e0+e1+e2+e3;
        float s8 = s4 + __shfl_xor(s4, 16, 64);
        float inv = 1.0f / s8;
        u16 h0 = f2bf(e0*inv + 1e-8f);
        u16 h1 = f2bf(e1*inv + 1e-8f);
        u16 h2 = f2bf(e2*inv + 1e-8f);
        u16 h3 = f2bf(e3*inv + 1e-8f);
        if (lane < 32) {
            int sb = quad*4, col = nt*16 + l15;
            pb[(sb+0)*72 + col] = h0;
            pb[(sb+1)*72 + col] = h1;
            pb[(sb+2)*72 + col] = h2;
            pb[(sb+3)*72 + col] = h3;
            psum[0] += bf2f(h0); psum[1] += bf2f(h1);
            psum[2] += bf2f(h2); psum[3] += bf2f(h3);
        }
    }
    __builtin_amdgcn_s_waitcnt(0xC07F);   // lgkmcnt(0): same-wave p-writes drained
    short8 ap0 = *reinterpret_cast<const short8*>(&pb[l15*72 + kq]);
    short8 ap1 = *reinterpret_cast<const short8*>(&pb[l15*72 + 32 + kq]);
#pragma unroll
    for (int dt = 0; dt < 16; dt++) {
        short8 nv0, nv1;
        if (dt < 14) {
            const u16* vn = vbase + (size_t)((dt+2)*16)*4096;
            nv0 = *reinterpret_cast<const short8*>(vn);
            nv1 = *reinterpret_cast<const short8*>(vn + 32);
        }
        acc[dt] = mfma16(ap0, v0[dt&1], acc[dt]);
        acc[dt] = mfma16(ap1, v1[dt&1], acc[dt]);
        if (dt < 14) { v0[dt&1] = nv0; v1[dt&1] = nv1; }
    }
#pragma unroll
    for (int off = 1; off < 16; off <<= 1) {
#pragma unroll
        for (int r = 0; r < 4; r++) psum[r] += __shfl_xor(psum[r], off, 64);
    }
    // per-wave direct output: no barrier, no LDS reduction
    const size_t base = ((size_t)b*64 + seg64) * 8;
    if (lane < 32 && l15 == 0) {
#pragma unroll
        for (int r = 0; r < 4; r++) den_part[base + quad*4 + r] = psum[r];
    }
    if (quad < 2) {
#pragma unroll
        for (int dt = 0; dt < 16; dt++) {
            int d0 = dt*16 + l15;
#pragma unroll
            for (int r = 0; r < 4; r++)
                num_part[(base + quad*4 + r)*256 + d0] = acc[dt][r];
        }
    }
}

// ---------------- per-iteration tail: updates -> GRU -> MLP -> slots (+q) ---
__global__ __launch_bounds__(768) void finalize(
        const float* __restrict__ slots_in, const float* __restrict__ num_part, const float* __restrict__ den_part,
        const u16* __restrict__ wihb, const float* __restrict__ bih,
        const u16* __restrict__ whhb, const float* __restrict__ bhh,
        const u16* __restrict__ w1b, const float* __restrict__ b1v,
        const u16* __restrict__ w2b, const float* __restrict__ b2v,
        const float* __restrict__ gff, const float* __restrict__ bff,
        float* __restrict__ slots_out,
        const u16* __restrict__ wqb, const float* __restrict__ bq,
        const float* __restrict__ gs, const float* __restrict__ bs,
        u16* __restrict__ qb, int do_q) {
    __shared__ u16 updb[16*264];
    __shared__ u16 prevb[16*264];
    __shared__ u16 lnb[16*264];
    __shared__ float gx[8*776];
    __shared__ float gh[8*776];
    __shared__ float snew[8*256];
    __shared__ float dsum_s[8];
    float* sfin = gx;    // reuse after gates consumed
    const int b = blockIdx.x;
    const int tid = threadIdx.x, wid = tid >> 6, lane = tid & 63;
    const int l15 = lane & 15, kq = (lane >> 4) * 8;
    if (tid < 8) {
        float ds = 0.f;
#pragma unroll 8
        for (int sg = 0; sg < 64; sg++) ds += den_part[((size_t)b*64 + sg)*8 + tid];
        dsum_s[tid] = ds;
    }
    __syncthreads();
    for (int idx = tid; idx < 2048; idx += 768) {
        int s = idx >> 8, d = idx & 255;
        float ns = 0.f;
#pragma unroll 8
        for (int sg = 0; sg < 64; sg++)
            ns += num_part[(((size_t)b*64 + sg)*8 + s)*256 + d];
        updb[s*264 + d] = f2bf(ns / dsum_s[s]);
        prevb[s*264 + d] = f2bf(slots_in[(size_t)(b*8 + s)*256 + d]);
        updb[(8+s)*264 + d] = 0;
        prevb[(8+s)*264 + d] = 0;
    }
    __syncthreads();
    short8 au[8], ap[8];
#pragma unroll
    for (int k = 0; k < 8; k++) {
        au[k] = *reinterpret_cast<const short8*>(&updb[l15*264 + k*32 + kq]);
        ap[k] = *reinterpret_cast<const short8*>(&prevb[l15*264 + k*32 + kq]);
    }
#pragma unroll
    for (int ct = 0; ct < 4; ct++) {
        int o0 = (wid*4 + ct)*16;
        f32x4 ax = (f32x4){0.f,0.f,0.f,0.f}, ah = (f32x4){0.f,0.f,0.f,0.f};
#pragma unroll
        for (int k = 0; k < 8; k++) {
            short8 bx = *reinterpret_cast<const short8*>(&wihb[(size_t)(o0 + l15)*256 + k*32 + kq]);
            short8 bh = *reinterpret_cast<const short8*>(&whhb[(size_t)(o0 + l15)*256 + k*32 + kq]);
            ax = mfma16(au[k], bx, ax);
            ah = mfma16(ap[k], bh, ah);
        }
        if (lane < 32) {
            int sb = (lane >> 4)*4, o = o0 + l15;
            float bxs = bih[o], bhs = bhh[o];
#pragma unroll
            for (int r = 0; r < 4; r++) {
                gx[(sb+r)*776 + o] = ax[r] + bxs;
                gh[(sb+r)*776 + o] = ah[r] + bhs;
            }
        }
    }
    __syncthreads();
    for (int idx = tid; idx < 2048; idx += 768) {
        int s = idx >> 8, j = idx & 255;
        float xr = gx[s*776 + j], xz = gx[s*776 + 256 + j], xn = gx[s*776 + 512 + j];
        float hr = gh[s*776 + j], hz = gh[s*776 + 256 + j], hn = gh[s*776 + 512 + j];
        float r_ = 1.f/(1.f + __expf(-(xr+hr)));
        float z_ = 1.f/(1.f + __expf(-(xz+hz)));
        float n_ = tanhf(xn + r_*hn);
        float pv = slots_in[(size_t)(b*8 + s)*256 + j];
        snew[s*256 + j] = (1.f - z_)*n_ + z_*pv;
    }
    __syncthreads();
    if (wid < 8) {
        int rr = wid;
        float4 v = reinterpret_cast<const float4*>(&snew[rr*256])[lane];
        float s = v.x + v.y + v.z + v.w;
        float ss = v.x*v.x + v.y*v.y + v.z*v.z + v.w*v.w;
#pragma unroll
        for (int off = 32; off >= 1; off >>= 1) { s += __shfl_xor(s, off, 64); ss += __shfl_xor(ss, off, 64); }
        float mean = s * (1.f/256.f);
        float rstd = rsqrtf(ss * (1.f/256.f) - mean*mean + 1e-5f);
        float4 g4 = reinterpret_cast<const float4*>(gff)[lane];
        float4 b4 = reinterpret_cast<const float4*>(bff)[lane];
        ushort4 o;
        o.x = f2bf((v.x-mean)*rstd*g4.x + b4.x);
        o.y = f2bf((v.y-mean)*rstd*g4.y + b4.y);
        o.z = f2bf((v.z-mean)*rstd*g4.z + b4.z);
        o.w = f2bf((v.w-mean)*rstd*g4.w + b4.w);
        *reinterpret_cast<ushort4*>(&lnb[rr*264 + lane*4]) = o;
    } else {
        ushort4 z = {0,0,0,0};
        *reinterpret_cast<ushort4*>(&lnb[wid*264 + lane*4]) = z;
        *reinterpret_cast<ushort4*>(&lnb[(wid+4)*264 + lane*4]) = z;
    }
    __syncthreads();
    short8 al[8];
#pragma unroll
    for (int k = 0; k < 8; k++) al[k] = *reinterpret_cast<const short8*>(&lnb[l15*264 + k*32 + kq]);
    for (int ct = wid; ct < 16; ct += 12) {
        int o0 = ct*16;
        f32x4 a = (f32x4){0.f,0.f,0.f,0.f};
#pragma unroll
        for (int k = 0; k < 8; k++) {
            short8 bw = *reinterpret_cast<const short8*>(&w1b[(size_t)(o0 + l15)*256 + k*32 + kq]);
            a = mfma16(al[k], bw, a);
        }
        if (lane < 32) {
            int sb = (lane >> 4)*4, o = o0 + l15;
            float bb = b1v[o];
#pragma unroll
            for (int r = 0; r < 4; r++)
                updb[(sb+r)*264 + o] = f2bf(fmaxf(a[r] + bb, 0.f));
        }
    }
    __syncthreads();
    short8 ah2[8];
#pragma unroll
    for (int k = 0; k < 8; k++) ah2[k] = *reinterpret_cast<const short8*>(&updb[l15*264 + k*32 + kq]);
    for (int ct = wid; ct < 16; ct += 12) {
        int o0 = ct*16;
        f32x4 a = (f32x4){0.f,0.f,0.f,0.f};
#pragma unroll
        for (int k = 0; k < 8; k++) {
            short8 bw = *reinterpret_cast<const short8*>(&w2b[(size_t)(o0 + l15)*256 + k*32 + kq]);
            a = mfma16(ah2[k], bw, a);
        }
        if (lane < 32) {
            int sb = (lane >> 4)*4, o = o0 + l15;
            float bb = b2v[o];
#pragma unroll
            for (int r = 0; r < 4; r++) {
                float vfin = snew[(sb+r)*256 + o] + a[r] + bb;
                slots_out[(size_t)(b*8 + sb + r)*256 + o] = vfin;
                sfin[(sb+r)*256 + o] = vfin;
            }
        }
    }
    if (!do_q) return;
    __syncthreads();
    // fused q projection for next iteration: q = LN(slots_new)@wq^T + bq
    if (wid < 8) {
        int rr = wid;
        float4 v = reinterpret_cast<const float4*>(&sfin[rr*256])[lane];
        float s = v.x + v.y + v.z + v.w;
        float ss = v.x*v.x + v.y*v.y + v.z*v.z + v.w*v.w;
#pragma unroll
        for (int off = 32; off >= 1; off >>= 1) { s += __shfl_xor(s, off, 64); ss += __shfl_xor(ss, off, 64); }
        float mean = s * (1.f/256.f);
        float rstd = rsqrtf(ss * (1.f/256.f) - mean*mean + 1e-5f);
        float4 g4 = reinterpret_cast<const float4*>(gs)[lane];
        float4 b4 = reinterpret_cast<const float4*>(bs)[lane];
        ushort4 o;
        o.x = f2bf((v.x-mean)*rstd*g4.x + b4.x);
        o.y = f2bf((v.y-mean)*rstd*g4.y + b4.y);
        o.z = f2bf((v.z-mean)*rstd*g4.z + b4.z);
        o.w = f2bf((v.w-mean)*rstd*g4.w + b4.w);
        *reinterpret_cast<ushort4*>(&lnb[rr*264 + lane*4]) = o;
    } else {
        ushort4 z = {0,0,0,0};
        *reinterpret_cast<ushort4*>(&lnb[wid*264 + lane*4]) = z;
        *reinterpret_cast<ushort4*>(&lnb[(wid+4)*264 + lane*4]) = z;
    }
    __syncthreads();
    short8 alq[8];
#pragma unroll
    for (int k = 0; k < 8; k++) alq[k] = *reinterpret_cast<const short8*>(&lnb[l15*264 + k*32 + kq]);
    for (int ct = wid; ct < 16; ct += 12) {
        int o0 = ct*16;
        f32x4 a = (f32x4){0.f,0.f,0.f,0.f};
#pragma unroll
        for (int k = 0; k < 8; k++) {
            short8 bw = *reinterpret_cast<const short8*>(&wqb[(size_t)(o0 + l15)*256 + k*32 + kq]);
            a = mfma16(alq[k], bw, a);
        }
        if (lane < 32) {
            int sb = (lane >> 4)*4, o = o0 + l15;
            float bb = bq[o];
#pragma unroll
            for (int r = 0; r < 4; r++)
                qb[(size_t)(b*8 + sb + r)*256 + o] = f2bf(a[r] + bb);
        }
    }
}

extern "C" void kernel_launch(void* const* d_in, const int* in_sizes, int n_in,
                              void* d_out, int out_size, void* d_ws, size_t ws_size,
                              hipStream_t stream) {
    (void)in_sizes; (void)n_in; (void)out_size;
    const float* inputs     = (const float*)d_in[0];
    const float* init_slots = (const float*)d_in[1];
    const float* wq  = (const float*)d_in[2];
    const float* bq  = (const float*)d_in[3];
    const float* wk  = (const float*)d_in[4];
    const float* bk  = (const float*)d_in[5];
    const float* wv  = (const float*)d_in[6];
    const float* bv  = (const float*)d_in[7];
    const float* wih = (const float*)d_in[8];
    const float* bih = (const float*)d_in[9];
    const float* whh = (const float*)d_in[10];
    const float* bhh = (const float*)d_in[11];
    const float* w1  = (const float*)d_in[12];
    const float* b1  = (const float*)d_in[13];
    const float* w2  = (const float*)d_in[14];
    const float* b2  = (const float*)d_in[15];
    const float* g_in = (const float*)d_in[16];
    const float* b_in = (const float*)d_in[17];
    const float* g_sl = (const float*)d_in[18];
    const float* b_sl = (const float*)d_in[19];
    const float* g_ff = (const float*)d_in[20];
    const float* b_ff = (const float*)d_in[21];

    char* ws = (char*)d_ws;
    size_t off = 0;
    auto alloc = [&](size_t bytes) -> void* {
        void* p = ws + off;
        off += (bytes + 255) & ~(size_t)255;
        return p;
    };
    u16* kx    = (u16*)alloc((size_t)GROWS * ND * 2);   // LN(x) bf16, then k bf16 in-place
    u16* vTb   = (u16*)alloc((size_t)GROWS * ND * 2);   // v bf16 transposed [b][d][n]
    u16* qbf   = (u16*)alloc((size_t)NB * NS * ND * 2);
    float* slots = (float*)alloc((size_t)NB * NS * ND * 4);
    float* nump  = (float*)alloc((size_t)NB * NSEG * NS * ND * 4);  // per-wave partials
    float* denp  = (float*)alloc((size_t)NB * NSEG * NS * 4);
    u16* wkvb = (u16*)alloc(131072 * 2);
    u16* wqb  = (u16*)alloc(65536 * 2);
    u16* wihb = (u16*)alloc(196608 * 2);
    u16* whhb = (u16*)alloc(196608 * 2);
    u16* w1b  = (u16*)alloc(65536 * 2);
    u16* w2b  = (u16*)alloc(65536 * 2);
    if (off > ws_size) return;  // insufficient workspace -> visible failure

    prep_w<<<2816, 256, 0, stream>>>(wk, wv, wq, wih, whh, w1, w2,
                                     wkvb, wqb, wihb, whhb, w1b, w2b);
    hipMemcpyAsync(slots, init_slots, (size_t)NB * NS * ND * 4,
                   hipMemcpyDeviceToDevice, stream);
    ln_cast<<<GROWS / 64, 256, 0, stream>>>(inputs, g_in, b_in, kx);
    gemm_kv<<<GROWS / 64, 256, 0, stream>>>(kx, wkvb, bk, bv, vTb);
    q_proj<<<NB, 256, 0, stream>>>(slots, wqb, bq, g_sl, b_sl, qbf);
    for (int it = 0; it < 3; it++) {
        attn<<<NB * 16, 256, 0, stream>>>(qbf, kx, vTb, nump, denp);
        float* outp = (it == 2) ? (float*)d_out : slots;
        finalize<<<NB, 768, 0, stream>>>(slots, nump, denp, wihb, bih, whhb, bhh,
                                         w1b, b1, w2b, b2, g_ff, b_ff, outp,
                                         wqb, bq, g_sl, b_sl, qbf, (it < 2) ? 1 : 0);
    }
}

// Round 5
// 744.424 us; speedup vs baseline: 1.3078x; 1.3078x over previous
//
#include <hip/hip_runtime.h>
#include <hip/hip_bf16.h>
#include <stdint.h>

typedef unsigned short u16;
typedef __attribute__((ext_vector_type(8))) short short8;
typedef __attribute__((ext_vector_type(4))) float f32x4;

#define NB 64
#define NN 4096
#define NS 8
#define ND 256
#define NSEG 16
#define GROWS (NB*NN)   // 262144

__device__ inline u16 f2bf(float f) {
    uint32_t u = __float_as_uint(f);
    u = (u + 0x7FFFu + ((u >> 16) & 1u)) >> 16;
    return (u16)u;
}
__device__ inline float bf2f(u16 h) {
    return __uint_as_float(((uint32_t)h) << 16);
}
__device__ inline f32x4 mfma16(short8 a, short8 b, f32x4 c) {
    return __builtin_amdgcn_mfma_f32_16x16x32_bf16(a, b, c, 0, 0, 0);
}

// ---------------- weight conversion fp32 -> bf16 (once per launch) ----------
// wv row-major; wk/wq TRANSPOSED casts (for the M = Wq^T Wk precompute).
// Total elements = 3*65536 + 2*196608 + 2*65536 = 720896 = 2816 blocks x 256.
__global__ __launch_bounds__(256) void prep_w(
        const float* __restrict__ wv, const float* __restrict__ wk, const float* __restrict__ wq,
        const float* __restrict__ wih, const float* __restrict__ whh,
        const float* __restrict__ w1, const float* __restrict__ w2,
        u16* __restrict__ wvb, u16* __restrict__ wkTb, u16* __restrict__ wqTb,
        u16* __restrict__ wihb, u16* __restrict__ whhb,
        u16* __restrict__ w1b, u16* __restrict__ w2b) {
    int i = blockIdx.x * 256 + threadIdx.x;
    if (i < 65536) { wvb[i] = f2bf(wv[i]); return; }
    i -= 65536;
    if (i < 65536) { wkTb[i] = f2bf(wk[(i & 255)*256 + (i >> 8)]); return; }
    i -= 65536;
    if (i < 65536) { wqTb[i] = f2bf(wq[(i & 255)*256 + (i >> 8)]); return; }
    i -= 65536;
    if (i < 196608) { wihb[i] = f2bf(wih[i]); return; }
    i -= 196608;
    if (i < 196608) { whhb[i] = f2bf(whh[i]); return; }
    i -= 196608;
    if (i < 65536) { w1b[i] = f2bf(w1[i]); return; }
    i -= 65536;
    if (i < 65536) w2b[i] = f2bf(w2[i]);   // bounds guard: no OOB on grid slip
}

// ---------------- M[d][m] = sum_o Wq[o,m]*Wk[o,d]; u[m] = sum_o Wq[o,m]*bk[o]
__global__ __launch_bounds__(256) void prep_M(
        const u16* __restrict__ wkTb, const u16* __restrict__ wqTb, u16* __restrict__ Mb,
        const float* __restrict__ wq, const float* __restrict__ bk, float* __restrict__ uvec) {
    if (blockIdx.x == 16) {
        int m = threadIdx.x;
        float acc = 0.f;
        for (int o = 0; o < 256; o++) acc += wq[o*256 + m] * bk[o];
        uvec[m] = acc;
        return;
    }
    const int d0 = blockIdx.x * 16;
    const int tid = threadIdx.x, wid = tid >> 6, lane = tid & 63;
    const int l15 = lane & 15, quad = lane >> 4, kq = quad * 8;
    short8 af[8];
#pragma unroll
    for (int k = 0; k < 8; k++)
        af[k] = *reinterpret_cast<const short8*>(&wkTb[(size_t)(d0 + l15)*256 + k*32 + kq]);
#pragma unroll
    for (int ct = 0; ct < 4; ct++) {
        int m0 = (wid*4 + ct)*16;
        f32x4 a = (f32x4){0.f,0.f,0.f,0.f};
#pragma unroll
        for (int k = 0; k < 8; k++) {
            short8 bw = *reinterpret_cast<const short8*>(&wqTb[(size_t)(m0 + l15)*256 + k*32 + kq]);
            a = mfma16(af[k], bw, a);
        }
        // C layout: col = lane&15 (m), row = quad*4+r (d) — all 16 rows valid
#pragma unroll
        for (int r = 0; r < 4; r++)
            Mb[(size_t)(d0 + quad*4 + r)*256 + m0 + l15] = f2bf(a[r]);
    }
}

// ---------------- streaming LN + cast: inputs fp32 -> xb AND xT (transposed)
// LDS tile [64][268] with XOR column swizzle so the transposed u16 gather is
// ~4-way instead of 32-way; xT stores are 128B-contiguous (8 lanes per d-row).
__global__ __launch_bounds__(256) void ln_cast(
        const float* __restrict__ inp, const float* __restrict__ g,
        const float* __restrict__ bt, u16* __restrict__ xb, u16* __restrict__ xT) {
    __shared__ u16 xs[64*268];
    const int tid = threadIdx.x, wid = tid >> 6, lane = tid & 63;
    const long r0 = (long)blockIdx.x * 64;
    const int rb = wid * 16;
    float4 g4 = reinterpret_cast<const float4*>(g)[lane];
    float4 b4 = reinterpret_cast<const float4*>(bt)[lane];
#pragma unroll 4
    for (int i = 0; i < 16; i++) {
        int row = rb + i;
        float4 v = reinterpret_cast<const float4*>(inp + (r0 + row)*256)[lane];
        float s = v.x + v.y + v.z + v.w;
        float ss = v.x*v.x + v.y*v.y + v.z*v.z + v.w*v.w;
#pragma unroll
        for (int off = 32; off >= 1; off >>= 1) { s += __shfl_xor(s, off, 64); ss += __shfl_xor(ss, off, 64); }
        float mean = s * (1.0f/256.0f);
        float rstd = rsqrtf(ss * (1.0f/256.0f) - mean*mean + 1e-5f);
        ushort4 o;
        o.x = f2bf((v.x-mean)*rstd*g4.x + b4.x);
        o.y = f2bf((v.y-mean)*rstd*g4.y + b4.y);
        o.z = f2bf((v.z-mean)*rstd*g4.z + b4.z);
        o.w = f2bf((v.w-mean)*rstd*g4.w + b4.w);
        reinterpret_cast<ushort4*>(xb + (r0 + row)*256)[lane] = o;
        int colb = (lane*4) ^ (((row >> 3) & 7) << 4);   // swizzled column
        *reinterpret_cast<ushort4*>(&xs[row*268 + colb]) = o;
    }
    __syncthreads();
    const long bb = r0 >> 12, nb0 = r0 & 4095;
#pragma unroll
    for (int pass = 0; pass < 8; pass++) {
        const int d = pass*32 + wid*8 + (lane >> 3);
        const int nc = (lane & 7) * 8;
        const int colr = d ^ ((lane & 7) << 4);   // n>>3 == lane&7 for this lane's rows
        short8 val;
#pragma unroll
        for (int s2 = 0; s2 < 8; s2++)
            val[s2] = (short)xs[(nc + s2)*268 + colr];
        *reinterpret_cast<short8*>(&xT[((size_t)bb*256 + d)*4096 + nb0 + nc]) = val;
    }
}

// ---------------- q~ projection (iteration 0): q~ = LN(slots) @ M^T, c = sn.u
__global__ __launch_bounds__(256) void q_proj(
        const float* __restrict__ slots, const u16* __restrict__ Mb,
        const float* __restrict__ uvec,
        const float* __restrict__ gs, const float* __restrict__ bs,
        u16* __restrict__ qb, float* __restrict__ cvec) {
    __shared__ u16 sn[16*264];
    const int b = blockIdx.x;
    const int tid = threadIdx.x, wid = tid >> 6, lane = tid & 63;
    const int l15 = lane & 15, kq = (lane >> 4) * 8;
    for (int rr = wid; rr < 8; rr += 4) {
        float4 v = reinterpret_cast<const float4*>(slots + (size_t)(b*8 + rr)*256)[lane];
        float s = v.x + v.y + v.z + v.w;
        float ss = v.x*v.x + v.y*v.y + v.z*v.z + v.w*v.w;
#pragma unroll
        for (int off = 32; off >= 1; off >>= 1) { s += __shfl_xor(s, off, 64); ss += __shfl_xor(ss, off, 64); }
        float mean = s * (1.f/256.f);
        float rstd = rsqrtf(ss * (1.f/256.f) - mean*mean + 1e-5f);
        float4 g4 = reinterpret_cast<const float4*>(gs)[lane];
        float4 b4 = reinterpret_cast<const float4*>(bs)[lane];
        ushort4 o;
        o.x = f2bf((v.x-mean)*rstd*g4.x + b4.x);
        o.y = f2bf((v.y-mean)*rstd*g4.y + b4.y);
        o.z = f2bf((v.z-mean)*rstd*g4.z + b4.z);
        o.w = f2bf((v.w-mean)*rstd*g4.w + b4.w);
        *reinterpret_cast<ushort4*>(&sn[rr*264 + lane*4]) = o;
    }
    {
        ushort4 z = {0,0,0,0};
        for (int rr = 8 + wid; rr < 16; rr += 4)
            *reinterpret_cast<ushort4*>(&sn[rr*264 + lane*4]) = z;
    }
    __syncthreads();
    {   // c_i = sn_i . u
        int s = tid >> 5, l = tid & 31;
        float p = 0.f;
#pragma unroll
        for (int i = 0; i < 8; i++)
            p += bf2f(sn[s*264 + l*8 + i]) * uvec[l*8 + i];
#pragma unroll
        for (int off = 16; off >= 1; off >>= 1) p += __shfl_xor(p, off, 64);
        if (l == 0) cvec[b*8 + s] = p;
    }
    short8 af[8];
#pragma unroll
    for (int k = 0; k < 8; k++) af[k] = *reinterpret_cast<const short8*>(&sn[l15*264 + k*32 + kq]);
#pragma unroll
    for (int ct = 0; ct < 4; ct++) {
        int o0 = (wid*4 + ct)*16;
        f32x4 a = (f32x4){0.f,0.f,0.f,0.f};
#pragma unroll
        for (int k = 0; k < 8; k++) {
            short8 bw = *reinterpret_cast<const short8*>(&Mb[(size_t)(o0 + l15)*256 + k*32 + kq]);
            a = mfma16(af[k], bw, a);
        }
        if (lane < 32) {
            int sb = (lane >> 4)*4;
#pragma unroll
            for (int r = 0; r < 4; r++)
                qb[(size_t)(b*8 + sb + r)*256 + o0 + l15] = f2bf(a[r]);
        }
    }
}

// ---------------- fused attention pass (round-2 structure, K/V-free) --------
// dots = q~ . x^ + c; accumulates U = sum_j p_ij x^_j into num_part.
__global__ __launch_bounds__(256) void attn(
        const u16* __restrict__ qt, const u16* __restrict__ xrow,
        const u16* __restrict__ xcol, const float* __restrict__ cvec,
        float* __restrict__ num_part, float* __restrict__ den_part) {
    __shared__ u16 pb_all[4][16*72];
    __shared__ float red[4][8][260];
    __shared__ float redd[4][8];
    const int b = blockIdx.x >> 4;
    const int seg = blockIdx.x & 15;
    const int tid = threadIdx.x, wid = tid >> 6, lane = tid & 63;
    const int l15 = lane & 15, quad = lane >> 4, kq = quad * 8;
    u16* pb = pb_all[wid];
    {   // zero P pad rows 8..15 of own wave's buffer
        short8 z = {0,0,0,0,0,0,0,0};
        int r8 = 8 + (lane >> 3), c8 = (lane & 7)*8;
        *reinterpret_cast<short8*>(&pb[r8*72 + c8]) = z;
    }
    // q~ A-fragment direct from global, rows >=8 zeroed
    short8 aq[8];
    {
        const u16* qrow = &qt[((size_t)b*8 + (l15 & 7))*256 + kq];
        short8 z = {0,0,0,0,0,0,0,0};
#pragma unroll
        for (int kk = 0; kk < 8; kk++) {
            short8 t = *reinterpret_cast<const short8*>(&qrow[kk*32]);
            aq[kk] = (l15 < 8) ? t : z;
        }
    }
    float cc[4];
#pragma unroll
    for (int r = 0; r < 4; r++) {
        int rowi = quad*4 + r;
        cc[r] = (rowi < 8) ? cvec[b*8 + rowi] : 0.f;
    }
    const int n_w = seg*256 + wid*64;
    const u16* kbase = &xrow[((size_t)b*4096 + n_w + l15)*256 + kq];
    const u16* vbase = &xcol[((size_t)b*256 + l15)*4096 + n_w + kq];
    f32x4 acc[16];
#pragma unroll
    for (int dt = 0; dt < 16; dt++) acc[dt] = (f32x4){0.f,0.f,0.f,0.f};
    float psum[4] = {0.f,0.f,0.f,0.f};
    short8 kf[8];
#pragma unroll
    for (int kk = 0; kk < 8; kk++) kf[kk] = *reinterpret_cast<const short8*>(&kbase[kk*32]);

    f32x4 dots[4];
#pragma unroll
    for (int nt = 0; nt < 4; nt++) {
        short8 kn[8];
        if (nt < 3) {
            const u16* kp = kbase + (size_t)((nt+1)*16)*256;
#pragma unroll
            for (int kk = 0; kk < 8; kk++) kn[kk] = *reinterpret_cast<const short8*>(&kp[kk*32]);
        }
        f32x4 d = (f32x4){0.f,0.f,0.f,0.f};
#pragma unroll
        for (int kk = 0; kk < 8; kk++) d = mfma16(aq[kk], kf[kk], d);
        dots[nt] = d;
        if (nt < 3) {
#pragma unroll
            for (int kk = 0; kk < 8; kk++) kf[kk] = kn[kk];
        }
    }
    // issue first two V d-tiles now: they fly during the softmax VALU phase
    short8 v0[2], v1[2];
    {
        v0[0] = *reinterpret_cast<const short8*>(vbase);
        v1[0] = *reinterpret_cast<const short8*>(vbase + 32);
        const u16* vr2 = vbase + (size_t)16*4096;
        v0[1] = *reinterpret_cast<const short8*>(vr2);
        v1[1] = *reinterpret_cast<const short8*>(vr2 + 32);
    }
#pragma unroll
    for (int nt = 0; nt < 4; nt++) {
        float t0 = (dots[nt][0] + cc[0])*0.0625f, t1 = (dots[nt][1] + cc[1])*0.0625f;
        float t2 = (dots[nt][2] + cc[2])*0.0625f, t3 = (dots[nt][3] + cc[3])*0.0625f;
        float m4 = fmaxf(fmaxf(t0,t1), fmaxf(t2,t3));
        float m8 = fmaxf(m4, __shfl_xor(m4, 16, 64));
        float e0 = __expf(t0-m8), e1 = __expf(t1-m8), e2 = __expf(t2-m8), e3 = __expf(t3-m8);
        float s4 = e0+e1+e2+e3;
        float s8 = s4 + __shfl_xor(s4, 16, 64);
        float inv = 1.0f / s8;
        u16 h0 = f2bf(e0*inv + 1e-8f);
        u16 h1 = f2bf(e1*inv + 1e-8f);
        u16 h2 = f2bf(e2*inv + 1e-8f);
        u16 h3 = f2bf(e3*inv + 1e-8f);
        if (lane < 32) {
            int sb = quad*4, col = nt*16 + l15;
            pb[(sb+0)*72 + col] = h0;
            pb[(sb+1)*72 + col] = h1;
            pb[(sb+2)*72 + col] = h2;
            pb[(sb+3)*72 + col] = h3;
            psum[0] += bf2f(h0); psum[1] += bf2f(h1);
            psum[2] += bf2f(h2); psum[3] += bf2f(h3);
        }
    }
    __builtin_amdgcn_s_waitcnt(0xC07F);   // lgkmcnt(0): same-wave p-writes drained
    short8 ap0 = *reinterpret_cast<const short8*>(&pb[l15*72 + kq]);
    short8 ap1 = *reinterpret_cast<const short8*>(&pb[l15*72 + 32 + kq]);
#pragma unroll
    for (int dt = 0; dt < 16; dt++) {
        short8 nv0, nv1;
        if (dt < 14) {
            const u16* vn = vbase + (size_t)((dt+2)*16)*4096;
            nv0 = *reinterpret_cast<const short8*>(vn);
            nv1 = *reinterpret_cast<const short8*>(vn + 32);
        }
        acc[dt] = mfma16(ap0, v0[dt&1], acc[dt]);
        acc[dt] = mfma16(ap1, v1[dt&1], acc[dt]);
        if (dt < 14) { v0[dt&1] = nv0; v1[dt&1] = nv1; }
    }
#pragma unroll
    for (int off = 1; off < 16; off <<= 1) {
#pragma unroll
        for (int r = 0; r < 4; r++) psum[r] += __shfl_xor(psum[r], off, 64);
    }
    // block-level reduction across the 4 waves through LDS (f32), then store
    if (lane < 32) {
        int sb = quad*4;
#pragma unroll
        for (int dt = 0; dt < 16; dt++) {
            int d0 = dt*16 + l15;
#pragma unroll
            for (int r = 0; r < 4; r++)
                red[wid][sb+r][d0] = acc[dt][r];
        }
        if (l15 == 0) {
#pragma unroll
            for (int r = 0; r < 4; r++) redd[wid][sb+r] = psum[r];
        }
    }
    __syncthreads();
    for (int idx = tid; idx < 2048; idx += 256) {
        int s = idx >> 8, d = idx & 255;
        float v = red[0][s][d] + red[1][s][d] + red[2][s][d] + red[3][s][d];
        num_part[((size_t)(b*16 + seg)*8 + s)*256 + d] = v;
    }
    if (tid < 8)
        den_part[(b*16 + seg)*8 + tid] = redd[0][tid] + redd[1][tid] + redd[2][tid] + redd[3][tid];
}

// ---------------- per-iteration tail: avg -> Wv -> GRU -> MLP -> slots (+q~)
__global__ __launch_bounds__(768) void finalize(
        const float* __restrict__ slots_in, const float* __restrict__ num_part, const float* __restrict__ den_part,
        const u16* __restrict__ wihb, const float* __restrict__ bih,
        const u16* __restrict__ whhb, const float* __restrict__ bhh,
        const u16* __restrict__ w1b, const float* __restrict__ b1v,
        const u16* __restrict__ w2b, const float* __restrict__ b2v,
        const u16* __restrict__ wvb, const float* __restrict__ bvv,
        const float* __restrict__ gff, const float* __restrict__ bff,
        float* __restrict__ slots_out,
        const u16* __restrict__ Mb, const float* __restrict__ uvec,
        const float* __restrict__ gs, const float* __restrict__ bs,
        u16* __restrict__ qb, float* __restrict__ cvec, int do_q) {
    __shared__ u16 updb[16*264];
    __shared__ u16 prevb[16*264];
    __shared__ u16 lnb[16*264];
    __shared__ float gx[8*776];
    __shared__ float gh[8*776];
    __shared__ float snew[8*256];
    __shared__ float dsum_s[8];
    float* sfin = gx;    // reuse after gates consumed
    const int b = blockIdx.x;
    const int tid = threadIdx.x, wid = tid >> 6, lane = tid & 63;
    const int l15 = lane & 15, kq = (lane >> 4) * 8;
    if (tid < 8) {
        float ds = 0.f;
#pragma unroll
        for (int sg = 0; sg < 16; sg++) ds += den_part[(b*16 + sg)*8 + tid];
        dsum_s[tid] = ds;
    }
    __syncthreads();
    for (int idx = tid; idx < 2048; idx += 768) {
        int s = idx >> 8, d = idx & 255;
        float ns = 0.f;
#pragma unroll
        for (int sg = 0; sg < 16; sg++)
            ns += num_part[((size_t)(b*16 + sg)*8 + s)*256 + d];
        updb[s*264 + d] = f2bf(ns / dsum_s[s]);   // avg = attn-weighted x^ mean
        prevb[s*264 + d] = f2bf(slots_in[(size_t)(b*8 + s)*256 + d]);
        updb[(8+s)*264 + d] = 0;
        prevb[(8+s)*264 + d] = 0;
        lnb[(8+s)*264 + d] = 0;
    }
    __syncthreads();
    // updates = avg @ Wv^T + bv  -> lnb rows 0..7
    {
        short8 av[8];
#pragma unroll
        for (int k = 0; k < 8; k++)
            av[k] = *reinterpret_cast<const short8*>(&updb[l15*264 + k*32 + kq]);
        for (int ct = wid; ct < 16; ct += 12) {
            int o0 = ct*16;
            f32x4 a = (f32x4){0.f,0.f,0.f,0.f};
#pragma unroll
            for (int k = 0; k < 8; k++) {
                short8 bw = *reinterpret_cast<const short8*>(&wvb[(size_t)(o0 + l15)*256 + k*32 + kq]);
                a = mfma16(av[k], bw, a);
            }
            if (lane < 32) {
                int sb = (lane >> 4)*4, o = o0 + l15;
                float bb2 = bvv[o];
#pragma unroll
                for (int r = 0; r < 4; r++)
                    lnb[(sb+r)*264 + o] = f2bf(a[r] + bb2);
            }
        }
    }
    __syncthreads();
    short8 au[8], ap[8];
#pragma unroll
    for (int k = 0; k < 8; k++) {
        au[k] = *reinterpret_cast<const short8*>(&lnb[l15*264 + k*32 + kq]);
        ap[k] = *reinterpret_cast<const short8*>(&prevb[l15*264 + k*32 + kq]);
    }
#pragma unroll
    for (int ct = 0; ct < 4; ct++) {
        int o0 = (wid*4 + ct)*16;
        f32x4 ax = (f32x4){0.f,0.f,0.f,0.f}, ah = (f32x4){0.f,0.f,0.f,0.f};
#pragma unroll
        for (int k = 0; k < 8; k++) {
            short8 bx = *reinterpret_cast<const short8*>(&wihb[(size_t)(o0 + l15)*256 + k*32 + kq]);
            short8 bh = *reinterpret_cast<const short8*>(&whhb[(size_t)(o0 + l15)*256 + k*32 + kq]);
            ax = mfma16(au[k], bx, ax);
            ah = mfma16(ap[k], bh, ah);
        }
        if (lane < 32) {
            int sb = (lane >> 4)*4, o = o0 + l15;
            float bxs = bih[o], bhs = bhh[o];
#pragma unroll
            for (int r = 0; r < 4; r++) {
                gx[(sb+r)*776 + o] = ax[r] + bxs;
                gh[(sb+r)*776 + o] = ah[r] + bhs;
            }
        }
    }
    __syncthreads();
    for (int idx = tid; idx < 2048; idx += 768) {
        int s = idx >> 8, j = idx & 255;
        float xr = gx[s*776 + j], xz = gx[s*776 + 256 + j], xn = gx[s*776 + 512 + j];
        float hr = gh[s*776 + j], hz = gh[s*776 + 256 + j], hn = gh[s*776 + 512 + j];
        float r_ = 1.f/(1.f + __expf(-(xr+hr)));
        float z_ = 1.f/(1.f + __expf(-(xz+hz)));
        float n_ = tanhf(xn + r_*hn);
        float pv = slots_in[(size_t)(b*8 + s)*256 + j];
        snew[s*256 + j] = (1.f - z_)*n_ + z_*pv;
    }
    __syncthreads();
    if (wid < 8) {
        int rr = wid;
        float4 v = reinterpret_cast<const float4*>(&snew[rr*256])[lane];
        float s = v.x + v.y + v.z + v.w;
        float ss = v.x*v.x + v.y*v.y + v.z*v.z + v.w*v.w;
#pragma unroll
        for (int off = 32; off >= 1; off >>= 1) { s += __shfl_xor(s, off, 64); ss += __shfl_xor(ss, off, 64); }
        float mean = s * (1.f/256.f);
        float rstd = rsqrtf(ss * (1.f/256.f) - mean*mean + 1e-5f);
        float4 g4 = reinterpret_cast<const float4*>(gff)[lane];
        float4 b4 = reinterpret_cast<const float4*>(bff)[lane];
        ushort4 o;
        o.x = f2bf((v.x-mean)*rstd*g4.x + b4.x);
        o.y = f2bf((v.y-mean)*rstd*g4.y + b4.y);
        o.z = f2bf((v.z-mean)*rstd*g4.z + b4.z);
        o.w = f2bf((v.w-mean)*rstd*g4.w + b4.w);
        *reinterpret_cast<ushort4*>(&lnb[rr*264 + lane*4]) = o;
    } else {
        ushort4 z = {0,0,0,0};
        *reinterpret_cast<ushort4*>(&lnb[wid*264 + lane*4]) = z;
        *reinterpret_cast<ushort4*>(&lnb[(wid+4)*264 + lane*4]) = z;
    }
    __syncthreads();
    short8 al[8];
#pragma unroll
    for (int k = 0; k < 8; k++) al[k] = *reinterpret_cast<const short8*>(&lnb[l15*264 + k*32 + kq]);
    for (int ct = wid; ct < 16; ct += 12) {
        int o0 = ct*16;
        f32x4 a = (f32x4){0.f,0.f,0.f,0.f};
#pragma unroll
        for (int k = 0; k < 8; k++) {
            short8 bw = *reinterpret_cast<const short8*>(&w1b[(size_t)(o0 + l15)*256 + k*32 + kq]);
            a = mfma16(al[k], bw, a);
        }
        if (lane < 32) {
            int sb = (lane >> 4)*4, o = o0 + l15;
            float bb = b1v[o];
#pragma unroll
            for (int r = 0; r < 4; r++)
                updb[(sb+r)*264 + o] = f2bf(fmaxf(a[r] + bb, 0.f));
        }
    }
    __syncthreads();
    short8 ah2[8];
#pragma unroll
    for (int k = 0; k < 8; k++) ah2[k] = *reinterpret_cast<const short8*>(&updb[l15*264 + k*32 + kq]);
    for (int ct = wid; ct < 16; ct += 12) {
        int o0 = ct*16;
        f32x4 a = (f32x4){0.f,0.f,0.f,0.f};
#pragma unroll
        for (int k = 0; k < 8; k++) {
            short8 bw = *reinterpret_cast<const short8*>(&w2b[(size_t)(o0 + l15)*256 + k*32 + kq]);
            a = mfma16(ah2[k], bw, a);
        }
        if (lane < 32) {
            int sb = (lane >> 4)*4, o = o0 + l15;
            float bb = b2v[o];
#pragma unroll
            for (int r = 0; r < 4; r++) {
                float vfin = snew[(sb+r)*256 + o] + a[r] + bb;
                slots_out[(size_t)(b*8 + sb + r)*256 + o] = vfin;
                sfin[(sb+r)*256 + o] = vfin;
            }
        }
    }
    if (!do_q) return;
    __syncthreads();
    // fused q~ projection for next iteration: q~ = LN(slots_new) @ M^T, c = sn.u
    if (wid < 8) {
        int rr = wid;
        float4 v = reinterpret_cast<const float4*>(&sfin[rr*256])[lane];
        float s = v.x + v.y + v.z + v.w;
        float ss = v.x*v.x + v.y*v.y + v.z*v.z + v.w*v.w;
#pragma unroll
        for (int off = 32; off >= 1; off >>= 1) { s += __shfl_xor(s, off, 64); ss += __shfl_xor(ss, off, 64); }
        float mean = s * (1.f/256.f);
        float rstd = rsqrtf(ss * (1.f/256.f) - mean*mean + 1e-5f);
        float4 g4 = reinterpret_cast<const float4*>(gs)[lane];
        float4 b4 = reinterpret_cast<const float4*>(bs)[lane];
        ushort4 o;
        o.x = f2bf((v.x-mean)*rstd*g4.x + b4.x);
        o.y = f2bf((v.y-mean)*rstd*g4.y + b4.y);
        o.z = f2bf((v.z-mean)*rstd*g4.z + b4.z);
        o.w = f2bf((v.w-mean)*rstd*g4.w + b4.w);
        *reinterpret_cast<ushort4*>(&lnb[rr*264 + lane*4]) = o;
    } else {
        ushort4 z = {0,0,0,0};
        *reinterpret_cast<ushort4*>(&lnb[wid*264 + lane*4]) = z;
        *reinterpret_cast<ushort4*>(&lnb[(wid+4)*264 + lane*4]) = z;
    }
    __syncthreads();
    if (tid < 256) {
        int s = tid >> 5, l = tid & 31;
        float p = 0.f;
#pragma unroll
        for (int i = 0; i < 8; i++)
            p += bf2f(lnb[s*264 + l*8 + i]) * uvec[l*8 + i];
#pragma unroll
        for (int off = 16; off >= 1; off >>= 1) p += __shfl_xor(p, off, 64);
        if (l == 0) cvec[b*8 + s] = p;
    }
    short8 alq[8];
#pragma unroll
    for (int k = 0; k < 8; k++) alq[k] = *reinterpret_cast<const short8*>(&lnb[l15*264 + k*32 + kq]);
    for (int ct = wid; ct < 16; ct += 12) {
        int o0 = ct*16;
        f32x4 a = (f32x4){0.f,0.f,0.f,0.f};
#pragma unroll
        for (int k = 0; k < 8; k++) {
            short8 bw = *reinterpret_cast<const short8*>(&Mb[(size_t)(o0 + l15)*256 + k*32 + kq]);
            a = mfma16(alq[k], bw, a);
        }
        if (lane < 32) {
            int sb = (lane >> 4)*4, o = o0 + l15;
#pragma unroll
            for (int r = 0; r < 4; r++)
                qb[(size_t)(b*8 + sb + r)*256 + o] = f2bf(a[r]);
        }
    }
}

extern "C" void kernel_launch(void* const* d_in, const int* in_sizes, int n_in,
                              void* d_out, int out_size, void* d_ws, size_t ws_size,
                              hipStream_t stream) {
    (void)in_sizes; (void)n_in; (void)out_size;
    const float* inputs     = (const float*)d_in[0];
    const float* init_slots = (const float*)d_in[1];
    const float* wq  = (const float*)d_in[2];
    const float* bq  = (const float*)d_in[3];  (void)bq;  // softmax-invariant, dropped
    const float* wk  = (const float*)d_in[4];
    const float* bk  = (const float*)d_in[5];
    const float* wv  = (const float*)d_in[6];
    const float* bv  = (const float*)d_in[7];
    const float* wih = (const float*)d_in[8];
    const float* bih = (const float*)d_in[9];
    const float* whh = (const float*)d_in[10];
    const float* bhh = (const float*)d_in[11];
    const float* w1  = (const float*)d_in[12];
    const float* b1  = (const float*)d_in[13];
    const float* w2  = (const float*)d_in[14];
    const float* b2  = (const float*)d_in[15];
    const float* g_in = (const float*)d_in[16];
    const float* b_in = (const float*)d_in[17];
    const float* g_sl = (const float*)d_in[18];
    const float* b_sl = (const float*)d_in[19];
    const float* g_ff = (const float*)d_in[20];
    const float* b_ff = (const float*)d_in[21];

    char* ws = (char*)d_ws;
    size_t off = 0;
    auto alloc = [&](size_t bytes) -> void* {
        void* p = ws + off;
        off += (bytes + 255) & ~(size_t)255;
        return p;
    };
    u16* xb    = (u16*)alloc((size_t)GROWS * ND * 2);   // LN(x) bf16 [b][n][d]
    u16* xT    = (u16*)alloc((size_t)GROWS * ND * 2);   // LN(x) bf16 transposed [b][d][n]
    u16* qbf   = (u16*)alloc((size_t)NB * NS * ND * 2); // q~ bf16
    float* slots = (float*)alloc((size_t)NB * NS * ND * 4);
    float* nump  = (float*)alloc((size_t)NB * NSEG * NS * ND * 4);
    float* denp  = (float*)alloc((size_t)NB * NSEG * NS * 4);
    float* cvec  = (float*)alloc((size_t)NB * NS * 4);
    float* uvec  = (float*)alloc(256 * 4);
    u16* wvb  = (u16*)alloc(65536 * 2);
    u16* wkTb = (u16*)alloc(65536 * 2);
    u16* wqTb = (u16*)alloc(65536 * 2);
    u16* Mb   = (u16*)alloc(65536 * 2);
    u16* wihb = (u16*)alloc(196608 * 2);
    u16* whhb = (u16*)alloc(196608 * 2);
    u16* w1b  = (u16*)alloc(65536 * 2);
    u16* w2b  = (u16*)alloc(65536 * 2);
    if (off > ws_size) return;  // insufficient workspace -> visible failure

    prep_w<<<2816, 256, 0, stream>>>(wv, wk, wq, wih, whh, w1, w2,
                                     wvb, wkTb, wqTb, wihb, whhb, w1b, w2b);
    prep_M<<<17, 256, 0, stream>>>(wkTb, wqTb, Mb, wq, bk, uvec);
    hipMemcpyAsync(slots, init_slots, (size_t)NB * NS * ND * 4,
                   hipMemcpyDeviceToDevice, stream);
    ln_cast<<<GROWS / 64, 256, 0, stream>>>(inputs, g_in, b_in, xb, xT);
    q_proj<<<NB, 256, 0, stream>>>(slots, Mb, uvec, g_sl, b_sl, qbf, cvec);
    for (int it = 0; it < 3; it++) {
        attn<<<NB * 16, 256, 0, stream>>>(qbf, xb, xT, cvec, nump, denp);
        float* outp = (it == 2) ? (float*)d_out : slots;
        finalize<<<NB, 768, 0, stream>>>(slots, nump, denp, wihb, bih, whhb, bhh,
                                         w1b, b1, w2b, b2, wvb, bv, g_ff, b_ff, outp,
                                         Mb, uvec, g_sl, b_sl, qbf, cvec, (it < 2) ? 1 : 0);
    }
}

// Round 6
// 738.942 us; speedup vs baseline: 1.3175x; 1.0074x over previous
//
#include <hip/hip_runtime.h>
#include <hip/hip_bf16.h>
#include <stdint.h>

typedef unsigned short u16;
typedef __attribute__((ext_vector_type(8))) short short8;
typedef __attribute__((ext_vector_type(4))) float f32x4;

#define NB 64
#define NN 4096
#define NS 8
#define ND 256
#define NSEG 16
#define GROWS (NB*NN)   // 262144

__device__ inline u16 f2bf(float f) {
    uint32_t u = __float_as_uint(f);
    u = (u + 0x7FFFu + ((u >> 16) & 1u)) >> 16;
    return (u16)u;
}
__device__ inline float bf2f(u16 h) {
    return __uint_as_float(((uint32_t)h) << 16);
}
__device__ inline f32x4 mfma16(short8 a, short8 b, f32x4 c) {
    return __builtin_amdgcn_mfma_f32_16x16x32_bf16(a, b, c, 0, 0, 0);
}

// ---------------- weight conversion fp32 -> bf16 (once per launch) ----------
// wv row-major; wk/wq TRANSPOSED casts (for the M = Wq^T Wk precompute).
// Total elements = 3*65536 + 2*196608 + 2*65536 = 720896 = 2816 blocks x 256.
__global__ __launch_bounds__(256) void prep_w(
        const float* __restrict__ wv, const float* __restrict__ wk, const float* __restrict__ wq,
        const float* __restrict__ wih, const float* __restrict__ whh,
        const float* __restrict__ w1, const float* __restrict__ w2,
        u16* __restrict__ wvb, u16* __restrict__ wkTb, u16* __restrict__ wqTb,
        u16* __restrict__ wihb, u16* __restrict__ whhb,
        u16* __restrict__ w1b, u16* __restrict__ w2b) {
    int i = blockIdx.x * 256 + threadIdx.x;
    if (i < 65536) { wvb[i] = f2bf(wv[i]); return; }
    i -= 65536;
    if (i < 65536) { wkTb[i] = f2bf(wk[(i & 255)*256 + (i >> 8)]); return; }
    i -= 65536;
    if (i < 65536) { wqTb[i] = f2bf(wq[(i & 255)*256 + (i >> 8)]); return; }
    i -= 65536;
    if (i < 196608) { wihb[i] = f2bf(wih[i]); return; }
    i -= 196608;
    if (i < 196608) { whhb[i] = f2bf(whh[i]); return; }
    i -= 196608;
    if (i < 65536) { w1b[i] = f2bf(w1[i]); return; }
    i -= 65536;
    if (i < 65536) w2b[i] = f2bf(w2[i]);   // bounds guard: no OOB on grid slip
}

// ---------------- M[d][m] = sum_o Wq[o,m]*Wk[o,d]; u[m] = sum_o Wq[o,m]*bk[o]
__global__ __launch_bounds__(256) void prep_M(
        const u16* __restrict__ wkTb, const u16* __restrict__ wqTb, u16* __restrict__ Mb,
        const float* __restrict__ wq, const float* __restrict__ bk, float* __restrict__ uvec) {
    if (blockIdx.x == 16) {
        int m = threadIdx.x;
        float acc = 0.f;
        for (int o = 0; o < 256; o++) acc += wq[o*256 + m] * bk[o];
        uvec[m] = acc;
        return;
    }
    const int d0 = blockIdx.x * 16;
    const int tid = threadIdx.x, wid = tid >> 6, lane = tid & 63;
    const int l15 = lane & 15, quad = lane >> 4, kq = quad * 8;
    short8 af[8];
#pragma unroll
    for (int k = 0; k < 8; k++)
        af[k] = *reinterpret_cast<const short8*>(&wkTb[(size_t)(d0 + l15)*256 + k*32 + kq]);
#pragma unroll
    for (int ct = 0; ct < 4; ct++) {
        int m0 = (wid*4 + ct)*16;
        f32x4 a = (f32x4){0.f,0.f,0.f,0.f};
#pragma unroll
        for (int k = 0; k < 8; k++) {
            short8 bw = *reinterpret_cast<const short8*>(&wqTb[(size_t)(m0 + l15)*256 + k*32 + kq]);
            a = mfma16(af[k], bw, a);
        }
        // C layout: col = lane&15 (m), row = quad*4+r (d) — all 16 rows valid
#pragma unroll
        for (int r = 0; r < 4; r++)
            Mb[(size_t)(d0 + quad*4 + r)*256 + m0 + l15] = f2bf(a[r]);
    }
}

// ---------------- streaming LN + cast: inputs fp32 -> xb AND xT (transposed)
// LDS tile [64][268] with XOR column swizzle so the transposed u16 gather is
// ~4-way instead of 32-way; xT stores are 128B-contiguous (8 lanes per d-row).
__global__ __launch_bounds__(256) void ln_cast(
        const float* __restrict__ inp, const float* __restrict__ g,
        const float* __restrict__ bt, u16* __restrict__ xb, u16* __restrict__ xT) {
    __shared__ u16 xs[64*268];
    const int tid = threadIdx.x, wid = tid >> 6, lane = tid & 63;
    const long r0 = (long)blockIdx.x * 64;
    const int rb = wid * 16;
    float4 g4 = reinterpret_cast<const float4*>(g)[lane];
    float4 b4 = reinterpret_cast<const float4*>(bt)[lane];
#pragma unroll 4
    for (int i = 0; i < 16; i++) {
        int row = rb + i;
        float4 v = reinterpret_cast<const float4*>(inp + (r0 + row)*256)[lane];
        float s = v.x + v.y + v.z + v.w;
        float ss = v.x*v.x + v.y*v.y + v.z*v.z + v.w*v.w;
#pragma unroll
        for (int off = 32; off >= 1; off >>= 1) { s += __shfl_xor(s, off, 64); ss += __shfl_xor(ss, off, 64); }
        float mean = s * (1.0f/256.0f);
        float rstd = rsqrtf(ss * (1.0f/256.0f) - mean*mean + 1e-5f);
        ushort4 o;
        o.x = f2bf((v.x-mean)*rstd*g4.x + b4.x);
        o.y = f2bf((v.y-mean)*rstd*g4.y + b4.y);
        o.z = f2bf((v.z-mean)*rstd*g4.z + b4.z);
        o.w = f2bf((v.w-mean)*rstd*g4.w + b4.w);
        reinterpret_cast<ushort4*>(xb + (r0 + row)*256)[lane] = o;
        int colb = (lane*4) ^ (((row >> 3) & 7) << 4);   // swizzled column
        *reinterpret_cast<ushort4*>(&xs[row*268 + colb]) = o;
    }
    __syncthreads();
    const long bb = r0 >> 12, nb0 = r0 & 4095;
#pragma unroll
    for (int pass = 0; pass < 8; pass++) {
        const int d = pass*32 + wid*8 + (lane >> 3);
        const int nc = (lane & 7) * 8;
        const int colr = d ^ ((lane & 7) << 4);   // n>>3 == lane&7 for this lane's rows
        short8 val;
#pragma unroll
        for (int s2 = 0; s2 < 8; s2++)
            val[s2] = (short)xs[(nc + s2)*268 + colr];
        *reinterpret_cast<short8*>(&xT[((size_t)bb*256 + d)*4096 + nb0 + nc]) = val;
    }
}

// ---------------- q~ projection (iteration 0): q~ = LN(slots) @ M^T, c = sn.u
__global__ __launch_bounds__(256) void q_proj(
        const float* __restrict__ slots, const u16* __restrict__ Mb,
        const float* __restrict__ uvec,
        const float* __restrict__ gs, const float* __restrict__ bs,
        u16* __restrict__ qb, float* __restrict__ cvec) {
    __shared__ u16 sn[16*264];
    const int b = blockIdx.x;
    const int tid = threadIdx.x, wid = tid >> 6, lane = tid & 63;
    const int l15 = lane & 15, kq = (lane >> 4) * 8;
    for (int rr = wid; rr < 8; rr += 4) {
        float4 v = reinterpret_cast<const float4*>(slots + (size_t)(b*8 + rr)*256)[lane];
        float s = v.x + v.y + v.z + v.w;
        float ss = v.x*v.x + v.y*v.y + v.z*v.z + v.w*v.w;
#pragma unroll
        for (int off = 32; off >= 1; off >>= 1) { s += __shfl_xor(s, off, 64); ss += __shfl_xor(ss, off, 64); }
        float mean = s * (1.f/256.f);
        float rstd = rsqrtf(ss * (1.f/256.f) - mean*mean + 1e-5f);
        float4 g4 = reinterpret_cast<const float4*>(gs)[lane];
        float4 b4 = reinterpret_cast<const float4*>(bs)[lane];
        ushort4 o;
        o.x = f2bf((v.x-mean)*rstd*g4.x + b4.x);
        o.y = f2bf((v.y-mean)*rstd*g4.y + b4.y);
        o.z = f2bf((v.z-mean)*rstd*g4.z + b4.z);
        o.w = f2bf((v.w-mean)*rstd*g4.w + b4.w);
        *reinterpret_cast<ushort4*>(&sn[rr*264 + lane*4]) = o;
    }
    {
        ushort4 z = {0,0,0,0};
        for (int rr = 8 + wid; rr < 16; rr += 4)
            *reinterpret_cast<ushort4*>(&sn[rr*264 + lane*4]) = z;
    }
    __syncthreads();
    {   // c_i = sn_i . u
        int s = tid >> 5, l = tid & 31;
        float p = 0.f;
#pragma unroll
        for (int i = 0; i < 8; i++)
            p += bf2f(sn[s*264 + l*8 + i]) * uvec[l*8 + i];
#pragma unroll
        for (int off = 16; off >= 1; off >>= 1) p += __shfl_xor(p, off, 64);
        if (l == 0) cvec[b*8 + s] = p;
    }
    short8 af[8];
#pragma unroll
    for (int k = 0; k < 8; k++) af[k] = *reinterpret_cast<const short8*>(&sn[l15*264 + k*32 + kq]);
#pragma unroll
    for (int ct = 0; ct < 4; ct++) {
        int o0 = (wid*4 + ct)*16;
        f32x4 a = (f32x4){0.f,0.f,0.f,0.f};
#pragma unroll
        for (int k = 0; k < 8; k++) {
            short8 bw = *reinterpret_cast<const short8*>(&Mb[(size_t)(o0 + l15)*256 + k*32 + kq]);
            a = mfma16(af[k], bw, a);
        }
        if (lane < 32) {
            int sb = (lane >> 4)*4;
#pragma unroll
            for (int r = 0; r < 4; r++)
                qb[(size_t)(b*8 + sb + r)*256 + o0 + l15] = f2bf(a[r]);
        }
    }
}

// ---------------- fused attention pass (K/V-free, occupancy-tuned) ----------
// dots = q~ . x^ + c; U = sum_j p_ij x^_j into num_part.
// LDS 26.2 KB + forced VGPR<=128 (launch_bounds 256,4): 4 blocks/CU -> the
// whole 1024-block grid is co-resident in one round (16 waves/CU).
// Softmax fused per nt-chunk; PV split into two d-half passes (acc[8]).
__global__ __launch_bounds__(256, 4) void attn(
        const u16* __restrict__ qt, const u16* __restrict__ xrow,
        const u16* __restrict__ xcol, const float* __restrict__ cvec,
        float* __restrict__ num_part, float* __restrict__ den_part) {
    __shared__ u16 pb_all[4][16*72];     // 9216 B
    __shared__ float red[4][8][132];     // 16896 B (d-half, two drain phases)
    __shared__ float redd[4][8];         // 128 B
    const int b = blockIdx.x >> 4;
    const int seg = blockIdx.x & 15;
    const int tid = threadIdx.x, wid = tid >> 6, lane = tid & 63;
    const int l15 = lane & 15, quad = lane >> 4, kq = quad * 8;
    u16* pb = pb_all[wid];
    {   // zero P pad rows 8..15 of own wave's buffer
        short8 z = {0,0,0,0,0,0,0,0};
        int r8 = 8 + (lane >> 3), c8 = (lane & 7)*8;
        *reinterpret_cast<short8*>(&pb[r8*72 + c8]) = z;
    }
    // q~ A-fragment direct from global, rows >=8 zeroed
    short8 aq[8];
    {
        const u16* qrow = &qt[((size_t)b*8 + (l15 & 7))*256 + kq];
        short8 z = {0,0,0,0,0,0,0,0};
#pragma unroll
        for (int kk = 0; kk < 8; kk++) {
            short8 t = *reinterpret_cast<const short8*>(&qrow[kk*32]);
            aq[kk] = (l15 < 8) ? t : z;
        }
    }
    float cc[4];
#pragma unroll
    for (int r = 0; r < 4; r++) {
        int rowi = quad*4 + r;
        cc[r] = (rowi < 8) ? cvec[b*8 + rowi] : 0.f;
    }
    const int n_w = seg*256 + wid*64;
    const u16* kbase = &xrow[((size_t)b*4096 + n_w + l15)*256 + kq];
    const u16* vbase = &xcol[((size_t)b*256 + l15)*4096 + n_w + kq];
    float psum[4] = {0.f,0.f,0.f,0.f};
    // early V prefetch (pass-0 tiles 0,1): lands during QK+softmax
    short8 v0[2], v1[2];
    v0[0] = *reinterpret_cast<const short8*>(vbase);
    v1[0] = *reinterpret_cast<const short8*>(vbase + 32);
    v0[1] = *reinterpret_cast<const short8*>(vbase + (size_t)16*4096);
    v1[1] = *reinterpret_cast<const short8*>(vbase + (size_t)16*4096 + 32);
    // QK with per-nt fused softmax (kn prefetch hides under softmax VALU)
    short8 kf[8];
#pragma unroll
    for (int kk = 0; kk < 8; kk++) kf[kk] = *reinterpret_cast<const short8*>(&kbase[kk*32]);
#pragma unroll
    for (int nt = 0; nt < 4; nt++) {
        f32x4 dd = (f32x4){0.f,0.f,0.f,0.f};
#pragma unroll
        for (int kk = 0; kk < 8; kk++) dd = mfma16(aq[kk], kf[kk], dd);
        short8 kn[8];
        if (nt < 3) {
            const u16* kp = kbase + (size_t)((nt+1)*16)*256;
#pragma unroll
            for (int kk = 0; kk < 8; kk++) kn[kk] = *reinterpret_cast<const short8*>(&kp[kk*32]);
        }
        float t0 = (dd[0] + cc[0])*0.0625f, t1 = (dd[1] + cc[1])*0.0625f;
        float t2 = (dd[2] + cc[2])*0.0625f, t3 = (dd[3] + cc[3])*0.0625f;
        float m4 = fmaxf(fmaxf(t0,t1), fmaxf(t2,t3));
        float m8 = fmaxf(m4, __shfl_xor(m4, 16, 64));
        float e0 = __expf(t0-m8), e1 = __expf(t1-m8), e2 = __expf(t2-m8), e3 = __expf(t3-m8);
        float s4 = e0+e1+e2+e3;
        float s8 = s4 + __shfl_xor(s4, 16, 64);
        float inv = 1.0f / s8;
        u16 h0 = f2bf(e0*inv + 1e-8f);
        u16 h1 = f2bf(e1*inv + 1e-8f);
        u16 h2 = f2bf(e2*inv + 1e-8f);
        u16 h3 = f2bf(e3*inv + 1e-8f);
        if (lane < 32) {
            int sb = quad*4, col = nt*16 + l15;
            pb[(sb+0)*72 + col] = h0;
            pb[(sb+1)*72 + col] = h1;
            pb[(sb+2)*72 + col] = h2;
            pb[(sb+3)*72 + col] = h3;
            psum[0] += bf2f(h0); psum[1] += bf2f(h1);
            psum[2] += bf2f(h2); psum[3] += bf2f(h3);
        }
        if (nt < 3) {
#pragma unroll
            for (int kk = 0; kk < 8; kk++) kf[kk] = kn[kk];
        }
    }
    __builtin_amdgcn_s_waitcnt(0xC07F);   // lgkmcnt(0): same-wave p-writes drained
    short8 ap0 = *reinterpret_cast<const short8*>(&pb[l15*72 + kq]);
    short8 ap1 = *reinterpret_cast<const short8*>(&pb[l15*72 + 32 + kq]);
    // ---- PV pass 0: d in [0,128) ----
    f32x4 acc8[8];
#pragma unroll
    for (int dt = 0; dt < 8; dt++) acc8[dt] = (f32x4){0.f,0.f,0.f,0.f};
#pragma unroll
    for (int dt = 0; dt < 8; dt++) {
        short8 nv0, nv1;
        if (dt < 6) {
            const u16* vn = vbase + (size_t)((dt+2)*16)*4096;
            nv0 = *reinterpret_cast<const short8*>(vn);
            nv1 = *reinterpret_cast<const short8*>(vn + 32);
        }
        acc8[dt] = mfma16(ap0, v0[dt&1], acc8[dt]);
        acc8[dt] = mfma16(ap1, v1[dt&1], acc8[dt]);
        if (dt < 6) { v0[dt&1] = nv0; v1[dt&1] = nv1; }
    }
    // issue pass-1's first two tiles (8,9): they fly during the reduce phase
    v0[0] = *reinterpret_cast<const short8*>(vbase + (size_t)(8*16)*4096);
    v1[0] = *reinterpret_cast<const short8*>(vbase + (size_t)(8*16)*4096 + 32);
    v0[1] = *reinterpret_cast<const short8*>(vbase + (size_t)(9*16)*4096);
    v1[1] = *reinterpret_cast<const short8*>(vbase + (size_t)(9*16)*4096 + 32);
#pragma unroll
    for (int off = 1; off < 16; off <<= 1) {
#pragma unroll
        for (int r = 0; r < 4; r++) psum[r] += __shfl_xor(psum[r], off, 64);
    }
    if (lane < 32) {
        int sb = quad*4;
#pragma unroll
        for (int dt = 0; dt < 8; dt++) {
            int d0 = dt*16 + l15;
#pragma unroll
            for (int r = 0; r < 4; r++)
                red[wid][sb+r][d0] = acc8[dt][r];
        }
        if (l15 == 0) {
#pragma unroll
            for (int r = 0; r < 4; r++) redd[wid][sb+r] = psum[r];
        }
    }
    __syncthreads();
    for (int idx = tid; idx < 1024; idx += 256) {
        int s = idx >> 7, d = idx & 127;
        float v = red[0][s][d] + red[1][s][d] + red[2][s][d] + red[3][s][d];
        num_part[((size_t)(b*16 + seg)*8 + s)*256 + d] = v;
    }
    if (tid < 8)
        den_part[(b*16 + seg)*8 + tid] = redd[0][tid] + redd[1][tid] + redd[2][tid] + redd[3][tid];
    __syncthreads();   // red free for reuse
    // ---- PV pass 1: d in [128,256) ----
#pragma unroll
    for (int dt = 0; dt < 8; dt++) acc8[dt] = (f32x4){0.f,0.f,0.f,0.f};
#pragma unroll
    for (int dt = 0; dt < 8; dt++) {
        short8 nv0, nv1;
        if (dt < 6) {
            const u16* vn = vbase + (size_t)((dt+10)*16)*4096;
            nv0 = *reinterpret_cast<const short8*>(vn);
            nv1 = *reinterpret_cast<const short8*>(vn + 32);
        }
        acc8[dt] = mfma16(ap0, v0[dt&1], acc8[dt]);
        acc8[dt] = mfma16(ap1, v1[dt&1], acc8[dt]);
        if (dt < 6) { v0[dt&1] = nv0; v1[dt&1] = nv1; }
    }
    if (lane < 32) {
        int sb = quad*4;
#pragma unroll
        for (int dt = 0; dt < 8; dt++) {
            int d0 = dt*16 + l15;
#pragma unroll
            for (int r = 0; r < 4; r++)
                red[wid][sb+r][d0] = acc8[dt][r];
        }
    }
    __syncthreads();
    for (int idx = tid; idx < 1024; idx += 256) {
        int s = idx >> 7, d = idx & 127;
        float v = red[0][s][d] + red[1][s][d] + red[2][s][d] + red[3][s][d];
        num_part[((size_t)(b*16 + seg)*8 + s)*256 + 128 + d] = v;
    }
}

// ---------------- per-iteration tail: avg -> Wv -> GRU -> MLP -> slots (+q~)
__global__ __launch_bounds__(768) void finalize(
        const float* __restrict__ slots_in, const float* __restrict__ num_part, const float* __restrict__ den_part,
        const u16* __restrict__ wihb, const float* __restrict__ bih,
        const u16* __restrict__ whhb, const float* __restrict__ bhh,
        const u16* __restrict__ w1b, const float* __restrict__ b1v,
        const u16* __restrict__ w2b, const float* __restrict__ b2v,
        const u16* __restrict__ wvb, const float* __restrict__ bvv,
        const float* __restrict__ gff, const float* __restrict__ bff,
        float* __restrict__ slots_out,
        const u16* __restrict__ Mb, const float* __restrict__ uvec,
        const float* __restrict__ gs, const float* __restrict__ bs,
        u16* __restrict__ qb, float* __restrict__ cvec, int do_q) {
    __shared__ u16 updb[16*264];
    __shared__ u16 prevb[16*264];
    __shared__ u16 lnb[16*264];
    __shared__ float gx[8*776];
    __shared__ float gh[8*776];
    __shared__ float snew[8*256];
    __shared__ float dsum_s[8];
    float* sfin = gx;    // reuse after gates consumed
    const int b = blockIdx.x;
    const int tid = threadIdx.x, wid = tid >> 6, lane = tid & 63;
    const int l15 = lane & 15, kq = (lane >> 4) * 8;
    if (tid < 8) {
        float ds = 0.f;
#pragma unroll
        for (int sg = 0; sg < 16; sg++) ds += den_part[(b*16 + sg)*8 + tid];
        dsum_s[tid] = ds;
    }
    __syncthreads();
    for (int idx = tid; idx < 2048; idx += 768) {
        int s = idx >> 8, d = idx & 255;
        float ns = 0.f;
#pragma unroll
        for (int sg = 0; sg < 16; sg++)
            ns += num_part[((size_t)(b*16 + sg)*8 + s)*256 + d];
        updb[s*264 + d] = f2bf(ns / dsum_s[s]);   // avg = attn-weighted x^ mean
        prevb[s*264 + d] = f2bf(slots_in[(size_t)(b*8 + s)*256 + d]);
        updb[(8+s)*264 + d] = 0;
        prevb[(8+s)*264 + d] = 0;
        lnb[(8+s)*264 + d] = 0;
    }
    __syncthreads();
    // updates = avg @ Wv^T + bv  -> lnb rows 0..7
    {
        short8 av[8];
#pragma unroll
        for (int k = 0; k < 8; k++)
            av[k] = *reinterpret_cast<const short8*>(&updb[l15*264 + k*32 + kq]);
        for (int ct = wid; ct < 16; ct += 12) {
            int o0 = ct*16;
            f32x4 a = (f32x4){0.f,0.f,0.f,0.f};
#pragma unroll
            for (int k = 0; k < 8; k++) {
                short8 bw = *reinterpret_cast<const short8*>(&wvb[(size_t)(o0 + l15)*256 + k*32 + kq]);
                a = mfma16(av[k], bw, a);
            }
            if (lane < 32) {
                int sb = (lane >> 4)*4, o = o0 + l15;
                float bb2 = bvv[o];
#pragma unroll
                for (int r = 0; r < 4; r++)
                    lnb[(sb+r)*264 + o] = f2bf(a[r] + bb2);
            }
        }
    }
    __syncthreads();
    short8 au[8], ap[8];
#pragma unroll
    for (int k = 0; k < 8; k++) {
        au[k] = *reinterpret_cast<const short8*>(&lnb[l15*264 + k*32 + kq]);
        ap[k] = *reinterpret_cast<const short8*>(&prevb[l15*264 + k*32 + kq]);
    }
#pragma unroll
    for (int ct = 0; ct < 4; ct++) {
        int o0 = (wid*4 + ct)*16;
        f32x4 ax = (f32x4){0.f,0.f,0.f,0.f}, ah = (f32x4){0.f,0.f,0.f,0.f};
#pragma unroll
        for (int k = 0; k < 8; k++) {
            short8 bx = *reinterpret_cast<const short8*>(&wihb[(size_t)(o0 + l15)*256 + k*32 + kq]);
            short8 bh = *reinterpret_cast<const short8*>(&whhb[(size_t)(o0 + l15)*256 + k*32 + kq]);
            ax = mfma16(au[k], bx, ax);
            ah = mfma16(ap[k], bh, ah);
        }
        if (lane < 32) {
            int sb = (lane >> 4)*4, o = o0 + l15;
            float bxs = bih[o], bhs = bhh[o];
#pragma unroll
            for (int r = 0; r < 4; r++) {
                gx[(sb+r)*776 + o] = ax[r] + bxs;
                gh[(sb+r)*776 + o] = ah[r] + bhs;
            }
        }
    }
    __syncthreads();
    for (int idx = tid; idx < 2048; idx += 768) {
        int s = idx >> 8, j = idx & 255;
        float xr = gx[s*776 + j], xz = gx[s*776 + 256 + j], xn = gx[s*776 + 512 + j];
        float hr = gh[s*776 + j], hz = gh[s*776 + 256 + j], hn = gh[s*776 + 512 + j];
        float r_ = 1.f/(1.f + __expf(-(xr+hr)));
        float z_ = 1.f/(1.f + __expf(-(xz+hz)));
        float n_ = tanhf(xn + r_*hn);
        float pv = slots_in[(size_t)(b*8 + s)*256 + j];
        snew[s*256 + j] = (1.f - z_)*n_ + z_*pv;
    }
    __syncthreads();
    if (wid < 8) {
        int rr = wid;
        float4 v = reinterpret_cast<const float4*>(&snew[rr*256])[lane];
        float s = v.x + v.y + v.z + v.w;
        float ss = v.x*v.x + v.y*v.y + v.z*v.z + v.w*v.w;
#pragma unroll
        for (int off = 32; off >= 1; off >>= 1) { s += __shfl_xor(s, off, 64); ss += __shfl_xor(ss, off, 64); }
        float mean = s * (1.f/256.f);
        float rstd = rsqrtf(ss * (1.f/256.f) - mean*mean + 1e-5f);
        float4 g4 = reinterpret_cast<const float4*>(gff)[lane];
        float4 b4 = reinterpret_cast<const float4*>(bff)[lane];
        ushort4 o;
        o.x = f2bf((v.x-mean)*rstd*g4.x + b4.x);
        o.y = f2bf((v.y-mean)*rstd*g4.y + b4.y);
        o.z = f2bf((v.z-mean)*rstd*g4.z + b4.z);
        o.w = f2bf((v.w-mean)*rstd*g4.w + b4.w);
        *reinterpret_cast<ushort4*>(&lnb[rr*264 + lane*4]) = o;
    } else {
        ushort4 z = {0,0,0,0};
        *reinterpret_cast<ushort4*>(&lnb[wid*264 + lane*4]) = z;
        *reinterpret_cast<ushort4*>(&lnb[(wid+4)*264 + lane*4]) = z;
    }
    __syncthreads();
    short8 al[8];
#pragma unroll
    for (int k = 0; k < 8; k++) al[k] = *reinterpret_cast<const short8*>(&lnb[l15*264 + k*32 + kq]);
    for (int ct = wid; ct < 16; ct += 12) {
        int o0 = ct*16;
        f32x4 a = (f32x4){0.f,0.f,0.f,0.f};
#pragma unroll
        for (int k = 0; k < 8; k++) {
            short8 bw = *reinterpret_cast<const short8*>(&w1b[(size_t)(o0 + l15)*256 + k*32 + kq]);
            a = mfma16(al[k], bw, a);
        }
        if (lane < 32) {
            int sb = (lane >> 4)*4, o = o0 + l15;
            float bb = b1v[o];
#pragma unroll
            for (int r = 0; r < 4; r++)
                updb[(sb+r)*264 + o] = f2bf(fmaxf(a[r] + bb, 0.f));
        }
    }
    __syncthreads();
    short8 ah2[8];
#pragma unroll
    for (int k = 0; k < 8; k++) ah2[k] = *reinterpret_cast<const short8*>(&updb[l15*264 + k*32 + kq]);
    for (int ct = wid; ct < 16; ct += 12) {
        int o0 = ct*16;
        f32x4 a = (f32x4){0.f,0.f,0.f,0.f};
#pragma unroll
        for (int k = 0; k < 8; k++) {
            short8 bw = *reinterpret_cast<const short8*>(&w2b[(size_t)(o0 + l15)*256 + k*32 + kq]);
            a = mfma16(ah2[k], bw, a);
        }
        if (lane < 32) {
            int sb = (lane >> 4)*4, o = o0 + l15;
            float bb = b2v[o];
#pragma unroll
            for (int r = 0; r < 4; r++) {
                float vfin = snew[(sb+r)*256 + o] + a[r] + bb;
                slots_out[(size_t)(b*8 + sb + r)*256 + o] = vfin;
                sfin[(sb+r)*256 + o] = vfin;
            }
        }
    }
    if (!do_q) return;
    __syncthreads();
    // fused q~ projection for next iteration: q~ = LN(slots_new) @ M^T, c = sn.u
    if (wid < 8) {
        int rr = wid;
        float4 v = reinterpret_cast<const float4*>(&sfin[rr*256])[lane];
        float s = v.x + v.y + v.z + v.w;
        float ss = v.x*v.x + v.y*v.y + v.z*v.z + v.w*v.w;
#pragma unroll
        for (int off = 32; off >= 1; off >>= 1) { s += __shfl_xor(s, off, 64); ss += __shfl_xor(ss, off, 64); }
        float mean = s * (1.f/256.f);
        float rstd = rsqrtf(ss * (1.f/256.f) - mean*mean + 1e-5f);
        float4 g4 = reinterpret_cast<const float4*>(gs)[lane];
        float4 b4 = reinterpret_cast<const float4*>(bs)[lane];
        ushort4 o;
        o.x = f2bf((v.x-mean)*rstd*g4.x + b4.x);
        o.y = f2bf((v.y-mean)*rstd*g4.y + b4.y);
        o.z = f2bf((v.z-mean)*rstd*g4.z + b4.z);
        o.w = f2bf((v.w-mean)*rstd*g4.w + b4.w);
        *reinterpret_cast<ushort4*>(&lnb[rr*264 + lane*4]) = o;
    } else {
        ushort4 z = {0,0,0,0};
        *reinterpret_cast<ushort4*>(&lnb[wid*264 + lane*4]) = z;
        *reinterpret_cast<ushort4*>(&lnb[(wid+4)*264 + lane*4]) = z;
    }
    __syncthreads();
    if (tid < 256) {
        int s = tid >> 5, l = tid & 31;
        float p = 0.f;
#pragma unroll
        for (int i = 0; i < 8; i++)
            p += bf2f(lnb[s*264 + l*8 + i]) * uvec[l*8 + i];
#pragma unroll
        for (int off = 16; off >= 1; off >>= 1) p += __shfl_xor(p, off, 64);
        if (l == 0) cvec[b*8 + s] = p;
    }
    short8 alq[8];
#pragma unroll
    for (int k = 0; k < 8; k++) alq[k] = *reinterpret_cast<const short8*>(&lnb[l15*264 + k*32 + kq]);
    for (int ct = wid; ct < 16; ct += 12) {
        int o0 = ct*16;
        f32x4 a = (f32x4){0.f,0.f,0.f,0.f};
#pragma unroll
        for (int k = 0; k < 8; k++) {
            short8 bw = *reinterpret_cast<const short8*>(&Mb[(size_t)(o0 + l15)*256 + k*32 + kq]);
            a = mfma16(alq[k], bw, a);
        }
        if (lane < 32) {
            int sb = (lane >> 4)*4, o = o0 + l15;
#pragma unroll
            for (int r = 0; r < 4; r++)
                qb[(size_t)(b*8 + sb + r)*256 + o] = f2bf(a[r]);
        }
    }
}

extern "C" void kernel_launch(void* const* d_in, const int* in_sizes, int n_in,
                              void* d_out, int out_size, void* d_ws, size_t ws_size,
                              hipStream_t stream) {
    (void)in_sizes; (void)n_in; (void)out_size;
    const float* inputs     = (const float*)d_in[0];
    const float* init_slots = (const float*)d_in[1];
    const float* wq  = (const float*)d_in[2];
    const float* bq  = (const float*)d_in[3];  (void)bq;  // softmax-invariant, dropped
    const float* wk  = (const float*)d_in[4];
    const float* bk  = (const float*)d_in[5];
    const float* wv  = (const float*)d_in[6];
    const float* bv  = (const float*)d_in[7];
    const float* wih = (const float*)d_in[8];
    const float* bih = (const float*)d_in[9];
    const float* whh = (const float*)d_in[10];
    const float* bhh = (const float*)d_in[11];
    const float* w1  = (const float*)d_in[12];
    const float* b1  = (const float*)d_in[13];
    const float* w2  = (const float*)d_in[14];
    const float* b2  = (const float*)d_in[15];
    const float* g_in = (const float*)d_in[16];
    const float* b_in = (const float*)d_in[17];
    const float* g_sl = (const float*)d_in[18];
    const float* b_sl = (const float*)d_in[19];
    const float* g_ff = (const float*)d_in[20];
    const float* b_ff = (const float*)d_in[21];

    char* ws = (char*)d_ws;
    size_t off = 0;
    auto alloc = [&](size_t bytes) -> void* {
        void* p = ws + off;
        off += (bytes + 255) & ~(size_t)255;
        return p;
    };
    u16* xb    = (u16*)alloc((size_t)GROWS * ND * 2);   // LN(x) bf16 [b][n][d]
    u16* xT    = (u16*)alloc((size_t)GROWS * ND * 2);   // LN(x) bf16 transposed [b][d][n]
    u16* qbf   = (u16*)alloc((size_t)NB * NS * ND * 2); // q~ bf16
    float* slots = (float*)alloc((size_t)NB * NS * ND * 4);
    float* nump  = (float*)alloc((size_t)NB * NSEG * NS * ND * 4);
    float* denp  = (float*)alloc((size_t)NB * NSEG * NS * 4);
    float* cvec  = (float*)alloc((size_t)NB * NS * 4);
    float* uvec  = (float*)alloc(256 * 4);
    u16* wvb  = (u16*)alloc(65536 * 2);
    u16* wkTb = (u16*)alloc(65536 * 2);
    u16* wqTb = (u16*)alloc(65536 * 2);
    u16* Mb   = (u16*)alloc(65536 * 2);
    u16* wihb = (u16*)alloc(196608 * 2);
    u16* whhb = (u16*)alloc(196608 * 2);
    u16* w1b  = (u16*)alloc(65536 * 2);
    u16* w2b  = (u16*)alloc(65536 * 2);
    if (off > ws_size) return;  // insufficient workspace -> visible failure

    prep_w<<<2816, 256, 0, stream>>>(wv, wk, wq, wih, whh, w1, w2,
                                     wvb, wkTb, wqTb, wihb, whhb, w1b, w2b);
    prep_M<<<17, 256, 0, stream>>>(wkTb, wqTb, Mb, wq, bk, uvec);
    hipMemcpyAsync(slots, init_slots, (size_t)NB * NS * ND * 4,
                   hipMemcpyDeviceToDevice, stream);
    ln_cast<<<GROWS / 64, 256, 0, stream>>>(inputs, g_in, b_in, xb, xT);
    q_proj<<<NB, 256, 0, stream>>>(slots, Mb, uvec, g_sl, b_sl, qbf, cvec);
    for (int it = 0; it < 3; it++) {
        attn<<<NB * 16, 256, 0, stream>>>(qbf, xb, xT, cvec, nump, denp);
        float* outp = (it == 2) ? (float*)d_out : slots;
        finalize<<<NB, 768, 0, stream>>>(slots, nump, denp, wihb, bih, whhb, bhh,
                                         w1b, b1, w2b, b2, wvb, bv, g_ff, b_ff, outp,
                                         Mb, uvec, g_sl, b_sl, qbf, cvec, (it < 2) ? 1 : 0);
    }
}

// Round 7
// 719.419 us; speedup vs baseline: 1.3533x; 1.0271x over previous
//
#include <hip/hip_runtime.h>
#include <hip/hip_bf16.h>
#include <stdint.h>

typedef unsigned short u16;
typedef __attribute__((ext_vector_type(8))) short short8;
typedef __attribute__((ext_vector_type(4))) float f32x4;

#define NB 64
#define NN 4096
#define NS 8
#define ND 256
#define NSEG 16
#define GROWS (NB*NN)   // 262144

__device__ inline u16 f2bf(float f) {
    uint32_t u = __float_as_uint(f);
    u = (u + 0x7FFFu + ((u >> 16) & 1u)) >> 16;
    return (u16)u;
}
__device__ inline float bf2f(u16 h) {
    return __uint_as_float(((uint32_t)h) << 16);
}
__device__ inline f32x4 mfma16(short8 a, short8 b, f32x4 c) {
    return __builtin_amdgcn_mfma_f32_16x16x32_bf16(a, b, c, 0, 0, 0);
}
__device__ inline void gload_lds16(const u16* g, u16* l) {
    __builtin_amdgcn_global_load_lds(
        (const __attribute__((address_space(1))) void*)g,
        (__attribute__((address_space(3))) void*)l,
        16, 0, 0);
}

// ---------------- weight conversion fp32 -> bf16 (once per launch) ----------
// wv row-major; wk/wq TRANSPOSED casts (for the M = Wq^T Wk precompute).
// Total elements = 3*65536 + 2*196608 + 2*65536 = 720896 = 2816 blocks x 256.
__global__ __launch_bounds__(256) void prep_w(
        const float* __restrict__ wv, const float* __restrict__ wk, const float* __restrict__ wq,
        const float* __restrict__ wih, const float* __restrict__ whh,
        const float* __restrict__ w1, const float* __restrict__ w2,
        u16* __restrict__ wvb, u16* __restrict__ wkTb, u16* __restrict__ wqTb,
        u16* __restrict__ wihb, u16* __restrict__ whhb,
        u16* __restrict__ w1b, u16* __restrict__ w2b) {
    int i = blockIdx.x * 256 + threadIdx.x;
    if (i < 65536) { wvb[i] = f2bf(wv[i]); return; }
    i -= 65536;
    if (i < 65536) { wkTb[i] = f2bf(wk[(i & 255)*256 + (i >> 8)]); return; }
    i -= 65536;
    if (i < 65536) { wqTb[i] = f2bf(wq[(i & 255)*256 + (i >> 8)]); return; }
    i -= 65536;
    if (i < 196608) { wihb[i] = f2bf(wih[i]); return; }
    i -= 196608;
    if (i < 196608) { whhb[i] = f2bf(whh[i]); return; }
    i -= 196608;
    if (i < 65536) { w1b[i] = f2bf(w1[i]); return; }
    i -= 65536;
    if (i < 65536) w2b[i] = f2bf(w2[i]);   // bounds guard: no OOB on grid slip
}

// ---------------- M[d][m] = sum_o Wq[o,m]*Wk[o,d]; u[m] = sum_o Wq[o,m]*bk[o]
__global__ __launch_bounds__(256) void prep_M(
        const u16* __restrict__ wkTb, const u16* __restrict__ wqTb, u16* __restrict__ Mb,
        const float* __restrict__ wq, const float* __restrict__ bk, float* __restrict__ uvec) {
    if (blockIdx.x == 16) {
        int m = threadIdx.x;
        float acc = 0.f;
        for (int o = 0; o < 256; o++) acc += wq[o*256 + m] * bk[o];
        uvec[m] = acc;
        return;
    }
    const int d0 = blockIdx.x * 16;
    const int tid = threadIdx.x, wid = tid >> 6, lane = tid & 63;
    const int l15 = lane & 15, quad = lane >> 4, kq = quad * 8;
    short8 af[8];
#pragma unroll
    for (int k = 0; k < 8; k++)
        af[k] = *reinterpret_cast<const short8*>(&wkTb[(size_t)(d0 + l15)*256 + k*32 + kq]);
#pragma unroll
    for (int ct = 0; ct < 4; ct++) {
        int m0 = (wid*4 + ct)*16;
        f32x4 a = (f32x4){0.f,0.f,0.f,0.f};
#pragma unroll
        for (int k = 0; k < 8; k++) {
            short8 bw = *reinterpret_cast<const short8*>(&wqTb[(size_t)(m0 + l15)*256 + k*32 + kq]);
            a = mfma16(af[k], bw, a);
        }
#pragma unroll
        for (int r = 0; r < 4; r++)
            Mb[(size_t)(d0 + quad*4 + r)*256 + m0 + l15] = f2bf(a[r]);
    }
}

// ---------------- streaming LN + cast: inputs fp32 -> xb bf16 (row-major only)
__global__ __launch_bounds__(256) void ln_cast(
        const float* __restrict__ inp, const float* __restrict__ g,
        const float* __restrict__ bt, u16* __restrict__ xb) {
    const int tid = threadIdx.x, wid = tid >> 6, lane = tid & 63;
    const long r0 = (long)blockIdx.x * 64 + wid * 16;
    float4 g4 = reinterpret_cast<const float4*>(g)[lane];
    float4 b4 = reinterpret_cast<const float4*>(bt)[lane];
#pragma unroll 4
    for (int i = 0; i < 16; i++) {
        long row = r0 + i;
        float4 v = reinterpret_cast<const float4*>(inp + row*256)[lane];
        float s = v.x + v.y + v.z + v.w;
        float ss = v.x*v.x + v.y*v.y + v.z*v.z + v.w*v.w;
#pragma unroll
        for (int off = 32; off >= 1; off >>= 1) { s += __shfl_xor(s, off, 64); ss += __shfl_xor(ss, off, 64); }
        float mean = s * (1.0f/256.0f);
        float rstd = rsqrtf(ss * (1.0f/256.0f) - mean*mean + 1e-5f);
        ushort4 o;
        o.x = f2bf((v.x-mean)*rstd*g4.x + b4.x);
        o.y = f2bf((v.y-mean)*rstd*g4.y + b4.y);
        o.z = f2bf((v.z-mean)*rstd*g4.z + b4.z);
        o.w = f2bf((v.w-mean)*rstd*g4.w + b4.w);
        reinterpret_cast<ushort4*>(xb + row*256)[lane] = o;
    }
}

// ---------------- q~ projection (iteration 0): q~ = LN(slots) @ M^T, c = sn.u
__global__ __launch_bounds__(256) void q_proj(
        const float* __restrict__ slots, const u16* __restrict__ Mb,
        const float* __restrict__ uvec,
        const float* __restrict__ gs, const float* __restrict__ bs,
        u16* __restrict__ qb, float* __restrict__ cvec) {
    __shared__ u16 sn[16*264];
    const int b = blockIdx.x;
    const int tid = threadIdx.x, wid = tid >> 6, lane = tid & 63;
    const int l15 = lane & 15, kq = (lane >> 4) * 8;
    for (int rr = wid; rr < 8; rr += 4) {
        float4 v = reinterpret_cast<const float4*>(slots + (size_t)(b*8 + rr)*256)[lane];
        float s = v.x + v.y + v.z + v.w;
        float ss = v.x*v.x + v.y*v.y + v.z*v.z + v.w*v.w;
#pragma unroll
        for (int off = 32; off >= 1; off >>= 1) { s += __shfl_xor(s, off, 64); ss += __shfl_xor(ss, off, 64); }
        float mean = s * (1.f/256.f);
        float rstd = rsqrtf(ss * (1.f/256.f) - mean*mean + 1e-5f);
        float4 g4 = reinterpret_cast<const float4*>(gs)[lane];
        float4 b4 = reinterpret_cast<const float4*>(bs)[lane];
        ushort4 o;
        o.x = f2bf((v.x-mean)*rstd*g4.x + b4.x);
        o.y = f2bf((v.y-mean)*rstd*g4.y + b4.y);
        o.z = f2bf((v.z-mean)*rstd*g4.z + b4.z);
        o.w = f2bf((v.w-mean)*rstd*g4.w + b4.w);
        *reinterpret_cast<ushort4*>(&sn[rr*264 + lane*4]) = o;
    }
    {
        ushort4 z = {0,0,0,0};
        for (int rr = 8 + wid; rr < 16; rr += 4)
            *reinterpret_cast<ushort4*>(&sn[rr*264 + lane*4]) = z;
    }
    __syncthreads();
    {   // c_i = sn_i . u
        int s = tid >> 5, l = tid & 31;
        float p = 0.f;
#pragma unroll
        for (int i = 0; i < 8; i++)
            p += bf2f(sn[s*264 + l*8 + i]) * uvec[l*8 + i];
#pragma unroll
        for (int off = 16; off >= 1; off >>= 1) p += __shfl_xor(p, off, 64);
        if (l == 0) cvec[b*8 + s] = p;
    }
    short8 af[8];
#pragma unroll
    for (int k = 0; k < 8; k++) af[k] = *reinterpret_cast<const short8*>(&sn[l15*264 + k*32 + kq]);
#pragma unroll
    for (int ct = 0; ct < 4; ct++) {
        int o0 = (wid*4 + ct)*16;
        f32x4 a = (f32x4){0.f,0.f,0.f,0.f};
#pragma unroll
        for (int k = 0; k < 8; k++) {
            short8 bw = *reinterpret_cast<const short8*>(&Mb[(size_t)(o0 + l15)*256 + k*32 + kq]);
            a = mfma16(af[k], bw, a);
        }
        if (lane < 32) {
            int sb = (lane >> 4)*4;
#pragma unroll
            for (int r = 0; r < 4; r++)
                qb[(size_t)(b*8 + sb + r)*256 + o0 + l15] = f2bf(a[r]);
        }
    }
}

// ---------------- fused attention: single x layout, LDS-transposed PV -------
// dots = q~.x^ + c from global xb; PV B-fragments from an async-staged,
// chunk-XOR-swizzled LDS tile (key = (r&7)^((r>>3)<<1)). Wave processes its
// 64-n strip as two serial 32-n chunks (16 KB tile, 2 blocks/CU). Cross-wave
// num reduction reuses the tile LDS after PV.
__global__ __launch_bounds__(256) void attn(
        const u16* __restrict__ qt, const u16* __restrict__ xrow,
        const float* __restrict__ cvec,
        float* __restrict__ num_part, float* __restrict__ den_part) {
    __shared__ u16 xt[4][32*256];    // 64 KB: per-wave x-tile (reused as f32 red)
    __shared__ u16 pb_all[4][16*36]; // 4.5 KB: per-wave P tile (32 n cols + pad)
    __shared__ float dpd[4][8];
    const int b = blockIdx.x >> 4;
    const int seg = blockIdx.x & 15;
    const int tid = threadIdx.x, wid = tid >> 6, lane = tid & 63;
    const int l15 = lane & 15, quad = lane >> 4, kq = quad * 8;
    u16* xw = xt[wid];
    u16* pb = pb_all[wid];
    const int n_w = seg*256 + wid*64;     // wave's 64-n strip

    // stage chunk 0 (local rows 0..31 = global n_w..n_w+31), swizzled source
    {
        const int half = lane >> 5, c = lane & 31;
#pragma unroll
        for (int i = 0; i < 16; i++) {
            const int r = i*2 + half;
            const int key = (r & 7) ^ ((r >> 3) << 1);
            gload_lds16(xrow + (size_t)(b*4096 + n_w + r)*256 + (c ^ key)*8, &xw[i*2*256]);
        }
    }
    // zero pb (softmax rewrites rows 0..7; rows 8..15 stay zero)
#pragma unroll
    for (int k2 = 0; k2 < 9; k2++) pb[lane + k2*64] = 0;

    // q~ A-fragment direct from global, rows >=8 zeroed
    short8 aq[8];
    {
        const u16* qrow = &qt[((size_t)b*8 + (l15 & 7))*256 + kq];
        short8 z = {0,0,0,0,0,0,0,0};
#pragma unroll
        for (int kk = 0; kk < 8; kk++) {
            short8 t = *reinterpret_cast<const short8*>(&qrow[kk*32]);
            aq[kk] = (l15 < 8) ? t : z;
        }
    }
    float cc[4];
#pragma unroll
    for (int r = 0; r < 4; r++) {
        int rowi = quad*4 + r;
        cc[r] = (rowi < 8) ? cvec[b*8 + rowi] : 0.f;
    }
    f32x4 acc[16];
#pragma unroll
    for (int dt = 0; dt < 16; dt++) acc[dt] = (f32x4){0.f,0.f,0.f,0.f};
    float psum[4] = {0.f,0.f,0.f,0.f};

    for (int ch = 0; ch < 2; ch++) {
        const int nc = n_w + ch*32;
        const u16* kbase = &xrow[((size_t)b*4096 + nc + l15)*256 + kq];
        // QK nt=0 (rows nc..nc+15) from global; nt=1 fragment prefetched
        short8 kf[8], kn[8];
#pragma unroll
        for (int kk = 0; kk < 8; kk++) kf[kk] = *reinterpret_cast<const short8*>(&kbase[kk*32]);
#pragma unroll
        for (int nt = 0; nt < 2; nt++) {
            f32x4 dd = (f32x4){0.f,0.f,0.f,0.f};
            if (nt == 0) {
#pragma unroll
                for (int kk = 0; kk < 8; kk++) dd = mfma16(aq[kk], kf[kk], dd);
                const u16* kp = kbase + (size_t)16*256;
#pragma unroll
                for (int kk = 0; kk < 8; kk++) kn[kk] = *reinterpret_cast<const short8*>(&kp[kk*32]);
            } else {
#pragma unroll
                for (int kk = 0; kk < 8; kk++) dd = mfma16(aq[kk], kn[kk], dd);
            }
            float t0 = (dd[0] + cc[0])*0.0625f, t1 = (dd[1] + cc[1])*0.0625f;
            float t2 = (dd[2] + cc[2])*0.0625f, t3 = (dd[3] + cc[3])*0.0625f;
            float m4 = fmaxf(fmaxf(t0,t1), fmaxf(t2,t3));
            float m8 = fmaxf(m4, __shfl_xor(m4, 16, 64));
            float e0 = __expf(t0-m8), e1 = __expf(t1-m8), e2 = __expf(t2-m8), e3 = __expf(t3-m8);
            float s4 = e0+e1+e2+e3;
            float s8 = s4 + __shfl_xor(s4, 16, 64);
            float inv = 1.0f / s8;
            u16 h0 = f2bf(e0*inv + 1e-8f);
            u16 h1 = f2bf(e1*inv + 1e-8f);
            u16 h2 = f2bf(e2*inv + 1e-8f);
            u16 h3 = f2bf(e3*inv + 1e-8f);
            if (lane < 32) {
                int sb = quad*4, col = nt*16 + l15;
                pb[(sb+0)*36 + col] = h0;
                pb[(sb+1)*36 + col] = h1;
                pb[(sb+2)*36 + col] = h2;
                pb[(sb+3)*36 + col] = h3;
                psum[0] += bf2f(h0); psum[1] += bf2f(h1);
                psum[2] += bf2f(h2); psum[3] += bf2f(h3);
            }
        }
        // wait: staged tile landed (vmcnt 0) + pb writes drained (lgkmcnt 0)
        __builtin_amdgcn_s_waitcnt(0x0070);
        __builtin_amdgcn_sched_barrier(0);
        short8 ap = *reinterpret_cast<const short8*>(&pb[l15*36 + kq]);
        // PV: B-fragment x[n = quad*8+j][d = dt*16+l15] via 8 swizzled scalars
        const int d = l15;   // d low bits vary with dt below
#pragma unroll
        for (int dt = 0; dt < 16; dt++) {
            const int dd2 = dt*16 + d;
            const int d3 = dd2 >> 3, d7 = dd2 & 7;
            const int rowb = quad*8*256 + d7;
            const int c3 = d3 ^ (quad << 1);
            short8 pv;
#pragma unroll
            for (int j = 0; j < 8; j++)
                pv[j] = (short)xw[rowb + j*256 + ((c3 ^ j) << 3)];
            acc[dt] = mfma16(ap, pv, acc[dt]);
        }
        // stage chunk 1 (after chunk-0 PV reads issued; QK1 covers the latency)
        if (ch == 0) {
            const int half = lane >> 5, c = lane & 31;
#pragma unroll
            for (int i = 0; i < 16; i++) {
                const int r = i*2 + half;
                const int key = (r & 7) ^ ((r >> 3) << 1);
                gload_lds16(xrow + (size_t)(b*4096 + n_w + 32 + r)*256 + (c ^ key)*8, &xw[i*2*256]);
            }
        }
    }
    // wave-local den reduce
#pragma unroll
    for (int off = 1; off < 16; off <<= 1) {
#pragma unroll
        for (int r = 0; r < 4; r++) psum[r] += __shfl_xor(psum[r], off, 64);
    }
    if (quad < 2 && l15 == 0) {
#pragma unroll
        for (int r = 0; r < 4; r++) dpd[wid][quad*4 + r] = psum[r];
    }
    // reuse xt[wid] as f32 red buffer (own region: no pre-barrier needed)
    float* rw = (float*)&xt[wid][0];
    if (lane < 32) {
        int sb = quad*4;
#pragma unroll
        for (int dt = 0; dt < 16; dt++) {
            int d0 = dt*16 + l15;
#pragma unroll
            for (int r = 0; r < 4; r++)
                rw[(sb+r)*256 + d0] = acc[dt][r];
        }
    }
    __syncthreads();
    const float* F = (const float*)&xt[0][0];   // region stride 4096 floats
    for (int idx = tid; idx < 2048; idx += 256) {
        float v = F[idx] + F[4096 + idx] + F[8192 + idx] + F[12288 + idx];
        num_part[((size_t)(b*16 + seg))*2048 + idx] = v;
    }
    if (tid < 8)
        den_part[(b*16 + seg)*8 + tid] = dpd[0][tid] + dpd[1][tid] + dpd[2][tid] + dpd[3][tid];
}

// ---------------- per-iteration tail: avg -> Wv -> GRU -> MLP -> slots (+q~)
__global__ __launch_bounds__(768) void finalize(
        const float* __restrict__ slots_in, const float* __restrict__ num_part, const float* __restrict__ den_part,
        const u16* __restrict__ wihb, const float* __restrict__ bih,
        const u16* __restrict__ whhb, const float* __restrict__ bhh,
        const u16* __restrict__ w1b, const float* __restrict__ b1v,
        const u16* __restrict__ w2b, const float* __restrict__ b2v,
        const u16* __restrict__ wvb, const float* __restrict__ bvv,
        const float* __restrict__ gff, const float* __restrict__ bff,
        float* __restrict__ slots_out,
        const u16* __restrict__ Mb, const float* __restrict__ uvec,
        const float* __restrict__ gs, const float* __restrict__ bs,
        u16* __restrict__ qb, float* __restrict__ cvec, int do_q) {
    __shared__ u16 updb[16*264];
    __shared__ u16 prevb[16*264];
    __shared__ u16 lnb[16*264];
    __shared__ float gx[8*776];
    __shared__ float gh[8*776];
    __shared__ float snew[8*256];
    __shared__ float dsum_s[8];
    float* sfin = gx;    // reuse after gates consumed
    const int b = blockIdx.x;
    const int tid = threadIdx.x, wid = tid >> 6, lane = tid & 63;
    const int l15 = lane & 15, kq = (lane >> 4) * 8;
    if (tid < 8) {
        float ds = 0.f;
#pragma unroll
        for (int sg = 0; sg < 16; sg++) ds += den_part[(b*16 + sg)*8 + tid];
        dsum_s[tid] = ds;
    }
    __syncthreads();
    for (int idx = tid; idx < 2048; idx += 768) {
        int s = idx >> 8, d = idx & 255;
        float ns = 0.f;
#pragma unroll
        for (int sg = 0; sg < 16; sg++)
            ns += num_part[((size_t)(b*16 + sg)*8 + s)*256 + d];
        updb[s*264 + d] = f2bf(ns / dsum_s[s]);   // avg = attn-weighted x^ mean
        prevb[s*264 + d] = f2bf(slots_in[(size_t)(b*8 + s)*256 + d]);
        updb[(8+s)*264 + d] = 0;
        prevb[(8+s)*264 + d] = 0;
        lnb[(8+s)*264 + d] = 0;
    }
    __syncthreads();
    // updates = avg @ Wv^T + bv  -> lnb rows 0..7
    {
        short8 av[8];
#pragma unroll
        for (int k = 0; k < 8; k++)
            av[k] = *reinterpret_cast<const short8*>(&updb[l15*264 + k*32 + kq]);
        for (int ct = wid; ct < 16; ct += 12) {
            int o0 = ct*16;
            f32x4 a = (f32x4){0.f,0.f,0.f,0.f};
#pragma unroll
            for (int k = 0; k < 8; k++) {
                short8 bw = *reinterpret_cast<const short8*>(&wvb[(size_t)(o0 + l15)*256 + k*32 + kq]);
                a = mfma16(av[k], bw, a);
            }
            if (lane < 32) {
                int sb = (lane >> 4)*4, o = o0 + l15;
                float bb2 = bvv[o];
#pragma unroll
                for (int r = 0; r < 4; r++)
                    lnb[(sb+r)*264 + o] = f2bf(a[r] + bb2);
            }
        }
    }
    __syncthreads();
    short8 au[8], ap[8];
#pragma unroll
    for (int k = 0; k < 8; k++) {
        au[k] = *reinterpret_cast<const short8*>(&lnb[l15*264 + k*32 + kq]);
        ap[k] = *reinterpret_cast<const short8*>(&prevb[l15*264 + k*32 + kq]);
    }
#pragma unroll
    for (int ct = 0; ct < 4; ct++) {
        int o0 = (wid*4 + ct)*16;
        f32x4 ax = (f32x4){0.f,0.f,0.f,0.f}, ah = (f32x4){0.f,0.f,0.f,0.f};
#pragma unroll
        for (int k = 0; k < 8; k++) {
            short8 bx = *reinterpret_cast<const short8*>(&wihb[(size_t)(o0 + l15)*256 + k*32 + kq]);
            short8 bh = *reinterpret_cast<const short8*>(&whhb[(size_t)(o0 + l15)*256 + k*32 + kq]);
            ax = mfma16(au[k], bx, ax);
            ah = mfma16(ap[k], bh, ah);
        }
        if (lane < 32) {
            int sb = (lane >> 4)*4, o = o0 + l15;
            float bxs = bih[o], bhs = bhh[o];
#pragma unroll
            for (int r = 0; r < 4; r++) {
                gx[(sb+r)*776 + o] = ax[r] + bxs;
                gh[(sb+r)*776 + o] = ah[r] + bhs;
            }
        }
    }
    __syncthreads();
    for (int idx = tid; idx < 2048; idx += 768) {
        int s = idx >> 8, j = idx & 255;
        float xr = gx[s*776 + j], xz = gx[s*776 + 256 + j], xn = gx[s*776 + 512 + j];
        float hr = gh[s*776 + j], hz = gh[s*776 + 256 + j], hn = gh[s*776 + 512 + j];
        float r_ = 1.f/(1.f + __expf(-(xr+hr)));
        float z_ = 1.f/(1.f + __expf(-(xz+hz)));
        float n_ = tanhf(xn + r_*hn);
        float pv = slots_in[(size_t)(b*8 + s)*256 + j];
        snew[s*256 + j] = (1.f - z_)*n_ + z_*pv;
    }
    __syncthreads();
    if (wid < 8) {
        int rr = wid;
        float4 v = reinterpret_cast<const float4*>(&snew[rr*256])[lane];
        float s = v.x + v.y + v.z + v.w;
        float ss = v.x*v.x + v.y*v.y + v.z*v.z + v.w*v.w;
#pragma unroll
        for (int off = 32; off >= 1; off >>= 1) { s += __shfl_xor(s, off, 64); ss += __shfl_xor(ss, off, 64); }
        float mean = s * (1.f/256.f);
        float rstd = rsqrtf(ss * (1.f/256.f) - mean*mean + 1e-5f);
        float4 g4 = reinterpret_cast<const float4*>(gff)[lane];
        float4 b4 = reinterpret_cast<const float4*>(bff)[lane];
        ushort4 o;
        o.x = f2bf((v.x-mean)*rstd*g4.x + b4.x);
        o.y = f2bf((v.y-mean)*rstd*g4.y + b4.y);
        o.z = f2bf((v.z-mean)*rstd*g4.z + b4.z);
        o.w = f2bf((v.w-mean)*rstd*g4.w + b4.w);
        *reinterpret_cast<ushort4*>(&lnb[rr*264 + lane*4]) = o;
    } else {
        ushort4 z = {0,0,0,0};
        *reinterpret_cast<ushort4*>(&lnb[wid*264 + lane*4]) = z;
        *reinterpret_cast<ushort4*>(&lnb[(wid+4)*264 + lane*4]) = z;
    }
    __syncthreads();
    short8 al[8];
#pragma unroll
    for (int k = 0; k < 8; k++) al[k] = *reinterpret_cast<const short8*>(&lnb[l15*264 + k*32 + kq]);
    for (int ct = wid; ct < 16; ct += 12) {
        int o0 = ct*16;
        f32x4 a = (f32x4){0.f,0.f,0.f,0.f};
#pragma unroll
        for (int k = 0; k < 8; k++) {
            short8 bw = *reinterpret_cast<const short8*>(&w1b[(size_t)(o0 + l15)*256 + k*32 + kq]);
            a = mfma16(al[k], bw, a);
        }
        if (lane < 32) {
            int sb = (lane >> 4)*4, o = o0 + l15;
            float bb = b1v[o];
#pragma unroll
            for (int r = 0; r < 4; r++)
                updb[(sb+r)*264 + o] = f2bf(fmaxf(a[r] + bb, 0.f));
        }
    }
    __syncthreads();
    short8 ah2[8];
#pragma unroll
    for (int k = 0; k < 8; k++) ah2[k] = *reinterpret_cast<const short8*>(&updb[l15*264 + k*32 + kq]);
    for (int ct = wid; ct < 16; ct += 12) {
        int o0 = ct*16;
        f32x4 a = (f32x4){0.f,0.f,0.f,0.f};
#pragma unroll
        for (int k = 0; k < 8; k++) {
            short8 bw = *reinterpret_cast<const short8*>(&w2b[(size_t)(o0 + l15)*256 + k*32 + kq]);
            a = mfma16(ah2[k], bw, a);
        }
        if (lane < 32) {
            int sb = (lane >> 4)*4, o = o0 + l15;
            float bb = b2v[o];
#pragma unroll
            for (int r = 0; r < 4; r++) {
                float vfin = snew[(sb+r)*256 + o] + a[r] + bb;
                slots_out[(size_t)(b*8 + sb + r)*256 + o] = vfin;
                sfin[(sb+r)*256 + o] = vfin;
            }
        }
    }
    if (!do_q) return;
    __syncthreads();
    // fused q~ projection for next iteration: q~ = LN(slots_new) @ M^T, c = sn.u
    if (wid < 8) {
        int rr = wid;
        float4 v = reinterpret_cast<const float4*>(&sfin[rr*256])[lane];
        float s = v.x + v.y + v.z + v.w;
        float ss = v.x*v.x + v.y*v.y + v.z*v.z + v.w*v.w;
#pragma unroll
        for (int off = 32; off >= 1; off >>= 1) { s += __shfl_xor(s, off, 64); ss += __shfl_xor(ss, off, 64); }
        float mean = s * (1.f/256.f);
        float rstd = rsqrtf(ss * (1.f/256.f) - mean*mean + 1e-5f);
        float4 g4 = reinterpret_cast<const float4*>(gs)[lane];
        float4 b4 = reinterpret_cast<const float4*>(bs)[lane];
        ushort4 o;
        o.x = f2bf((v.x-mean)*rstd*g4.x + b4.x);
        o.y = f2bf((v.y-mean)*rstd*g4.y + b4.y);
        o.z = f2bf((v.z-mean)*rstd*g4.z + b4.z);
        o.w = f2bf((v.w-mean)*rstd*g4.w + b4.w);
        *reinterpret_cast<ushort4*>(&lnb[rr*264 + lane*4]) = o;
    } else {
        ushort4 z = {0,0,0,0};
        *reinterpret_cast<ushort4*>(&lnb[wid*264 + lane*4]) = z;
        *reinterpret_cast<ushort4*>(&lnb[(wid+4)*264 + lane*4]) = z;
    }
    __syncthreads();
    if (tid < 256) {
        int s = tid >> 5, l = tid & 31;
        float p = 0.f;
#pragma unroll
        for (int i = 0; i < 8; i++)
            p += bf2f(lnb[s*264 + l*8 + i]) * uvec[l*8 + i];
#pragma unroll
        for (int off = 16; off >= 1; off >>= 1) p += __shfl_xor(p, off, 64);
        if (l == 0) cvec[b*8 + s] = p;
    }
    short8 alq[8];
#pragma unroll
    for (int k = 0; k < 8; k++) alq[k] = *reinterpret_cast<const short8*>(&lnb[l15*264 + k*32 + kq]);
    for (int ct = wid; ct < 16; ct += 12) {
        int o0 = ct*16;
        f32x4 a = (f32x4){0.f,0.f,0.f,0.f};
#pragma unroll
        for (int k = 0; k < 8; k++) {
            short8 bw = *reinterpret_cast<const short8*>(&Mb[(size_t)(o0 + l15)*256 + k*32 + kq]);
            a = mfma16(alq[k], bw, a);
        }
        if (lane < 32) {
            int sb = (lane >> 4)*4, o = o0 + l15;
#pragma unroll
            for (int r = 0; r < 4; r++)
                qb[(size_t)(b*8 + sb + r)*256 + o] = f2bf(a[r]);
        }
    }
}

extern "C" void kernel_launch(void* const* d_in, const int* in_sizes, int n_in,
                              void* d_out, int out_size, void* d_ws, size_t ws_size,
                              hipStream_t stream) {
    (void)in_sizes; (void)n_in; (void)out_size;
    const float* inputs     = (const float*)d_in[0];
    const float* init_slots = (const float*)d_in[1];
    const float* wq  = (const float*)d_in[2];
    const float* bq  = (const float*)d_in[3];  (void)bq;  // softmax-invariant, dropped
    const float* wk  = (const float*)d_in[4];
    const float* bk  = (const float*)d_in[5];
    const float* wv  = (const float*)d_in[6];
    const float* bv  = (const float*)d_in[7];
    const float* wih = (const float*)d_in[8];
    const float* bih = (const float*)d_in[9];
    const float* whh = (const float*)d_in[10];
    const float* bhh = (const float*)d_in[11];
    const float* w1  = (const float*)d_in[12];
    const float* b1  = (const float*)d_in[13];
    const float* w2  = (const float*)d_in[14];
    const float* b2  = (const float*)d_in[15];
    const float* g_in = (const float*)d_in[16];
    const float* b_in = (const float*)d_in[17];
    const float* g_sl = (const float*)d_in[18];
    const float* b_sl = (const float*)d_in[19];
    const float* g_ff = (const float*)d_in[20];
    const float* b_ff = (const float*)d_in[21];

    char* ws = (char*)d_ws;
    size_t off = 0;
    auto alloc = [&](size_t bytes) -> void* {
        void* p = ws + off;
        off += (bytes + 255) & ~(size_t)255;
        return p;
    };
    u16* xb    = (u16*)alloc((size_t)GROWS * ND * 2);   // LN(x) bf16 [b][n][d]
    u16* qbf   = (u16*)alloc((size_t)NB * NS * ND * 2); // q~ bf16
    float* slots = (float*)alloc((size_t)NB * NS * ND * 4);
    float* nump  = (float*)alloc((size_t)NB * NSEG * NS * ND * 4);
    float* denp  = (float*)alloc((size_t)NB * NSEG * NS * 4);
    float* cvec  = (float*)alloc((size_t)NB * NS * 4);
    float* uvec  = (float*)alloc(256 * 4);
    u16* wvb  = (u16*)alloc(65536 * 2);
    u16* wkTb = (u16*)alloc(65536 * 2);
    u16* wqTb = (u16*)alloc(65536 * 2);
    u16* Mb   = (u16*)alloc(65536 * 2);
    u16* wihb = (u16*)alloc(196608 * 2);
    u16* whhb = (u16*)alloc(196608 * 2);
    u16* w1b  = (u16*)alloc(65536 * 2);
    u16* w2b  = (u16*)alloc(65536 * 2);
    if (off > ws_size) return;  // insufficient workspace -> visible failure

    prep_w<<<2816, 256, 0, stream>>>(wv, wk, wq, wih, whh, w1, w2,
                                     wvb, wkTb, wqTb, wihb, whhb, w1b, w2b);
    prep_M<<<17, 256, 0, stream>>>(wkTb, wqTb, Mb, wq, bk, uvec);
    hipMemcpyAsync(slots, init_slots, (size_t)NB * NS * ND * 4,
                   hipMemcpyDeviceToDevice, stream);
    ln_cast<<<GROWS / 64, 256, 0, stream>>>(inputs, g_in, b_in, xb);
    q_proj<<<NB, 256, 0, stream>>>(slots, Mb, uvec, g_sl, b_sl, qbf, cvec);
    for (int it = 0; it < 3; it++) {
        attn<<<NB * 16, 256, 0, stream>>>(qbf, xb, cvec, nump, denp);
        float* outp = (it == 2) ? (float*)d_out : slots;
        finalize<<<NB, 768, 0, stream>>>(slots, nump, denp, wihb, bih, whhb, bhh,
                                         w1b, b1, w2b, b2, wvb, bv, g_ff, b_ff, outp,
                                         Mb, uvec, g_sl, b_sl, qbf, cvec, (it < 2) ? 1 : 0);
    }
}

// Round 9
// 646.038 us; speedup vs baseline: 1.5070x; 1.1136x over previous
//
#include <hip/hip_runtime.h>
#include <hip/hip_bf16.h>
#include <stdint.h>

typedef unsigned short u16;
typedef __attribute__((ext_vector_type(8))) short short8;
typedef __attribute__((ext_vector_type(4))) float f32x4;

#define NB 64
#define NN 4096
#define NS 8
#define ND 256
#define NSEG 8
#define GROWS (NB*NN)   // 262144

__device__ inline u16 f2bf(float f) {
    uint32_t u = __float_as_uint(f);
    u = (u + 0x7FFFu + ((u >> 16) & 1u)) >> 16;
    return (u16)u;
}
__device__ inline float bf2f(u16 h) {
    return __uint_as_float(((uint32_t)h) << 16);
}
__device__ inline f32x4 mfma16(short8 a, short8 b, f32x4 c) {
    return __builtin_amdgcn_mfma_f32_16x16x32_bf16(a, b, c, 0, 0, 0);
}
__device__ inline void gload_lds16(const u16* g, u16* l) {
    __builtin_amdgcn_global_load_lds(
        (const __attribute__((address_space(1))) void*)g,
        (__attribute__((address_space(3))) void*)l,
        16, 0, 0);
}

// ---------------- weight conversion fp32 -> bf16 (once per launch) ----------
__global__ __launch_bounds__(256) void prep_w(
        const float* __restrict__ wv, const float* __restrict__ wk, const float* __restrict__ wq,
        const float* __restrict__ wih, const float* __restrict__ whh,
        const float* __restrict__ w1, const float* __restrict__ w2,
        u16* __restrict__ wvb, u16* __restrict__ wkTb, u16* __restrict__ wqTb,
        u16* __restrict__ wihb, u16* __restrict__ whhb,
        u16* __restrict__ w1b, u16* __restrict__ w2b) {
    int i = blockIdx.x * 256 + threadIdx.x;
    if (i < 65536) { wvb[i] = f2bf(wv[i]); return; }
    i -= 65536;
    if (i < 65536) { wkTb[i] = f2bf(wk[(i & 255)*256 + (i >> 8)]); return; }
    i -= 65536;
    if (i < 65536) { wqTb[i] = f2bf(wq[(i & 255)*256 + (i >> 8)]); return; }
    i -= 65536;
    if (i < 196608) { wihb[i] = f2bf(wih[i]); return; }
    i -= 196608;
    if (i < 196608) { whhb[i] = f2bf(whh[i]); return; }
    i -= 196608;
    if (i < 65536) { w1b[i] = f2bf(w1[i]); return; }
    i -= 65536;
    if (i < 65536) w2b[i] = f2bf(w2[i]);   // bounds guard: no OOB on grid slip
}

// ---------------- M[d][m] = sum_o Wq[o,m]*Wk[o,d]; u[m] = sum_o Wq[o,m]*bk[o]
__global__ __launch_bounds__(256) void prep_M(
        const u16* __restrict__ wkTb, const u16* __restrict__ wqTb, u16* __restrict__ Mb,
        const float* __restrict__ wq, const float* __restrict__ bk, float* __restrict__ uvec) {
    if (blockIdx.x == 16) {
        int m = threadIdx.x;
        float acc = 0.f;
        for (int o = 0; o < 256; o++) acc += wq[o*256 + m] * bk[o];
        uvec[m] = acc;
        return;
    }
    const int d0 = blockIdx.x * 16;
    const int tid = threadIdx.x, wid = tid >> 6, lane = tid & 63;
    const int l15 = lane & 15, quad = lane >> 4, kq = quad * 8;
    short8 af[8];
#pragma unroll
    for (int k = 0; k < 8; k++)
        af[k] = *reinterpret_cast<const short8*>(&wkTb[(size_t)(d0 + l15)*256 + k*32 + kq]);
#pragma unroll
    for (int ct = 0; ct < 4; ct++) {
        int m0 = (wid*4 + ct)*16;
        f32x4 a = (f32x4){0.f,0.f,0.f,0.f};
#pragma unroll
        for (int k = 0; k < 8; k++) {
            short8 bw = *reinterpret_cast<const short8*>(&wqTb[(size_t)(m0 + l15)*256 + k*32 + kq]);
            a = mfma16(af[k], bw, a);
        }
#pragma unroll
        for (int r = 0; r < 4; r++)
            Mb[(size_t)(d0 + quad*4 + r)*256 + m0 + l15] = f2bf(a[r]);
    }
}

// ---------------- streaming LN + cast: inputs fp32 -> xb bf16 (row-major) ---
__global__ __launch_bounds__(256) void ln_cast(
        const float* __restrict__ inp, const float* __restrict__ g,
        const float* __restrict__ bt, u16* __restrict__ xb) {
    const int tid = threadIdx.x, wid = tid >> 6, lane = tid & 63;
    const long r0 = (long)blockIdx.x * 64 + wid * 16;
    float4 g4 = reinterpret_cast<const float4*>(g)[lane];
    float4 b4 = reinterpret_cast<const float4*>(bt)[lane];
#pragma unroll 4
    for (int i = 0; i < 16; i++) {
        long row = r0 + i;
        float4 v = reinterpret_cast<const float4*>(inp + row*256)[lane];
        float s = v.x + v.y + v.z + v.w;
        float ss = v.x*v.x + v.y*v.y + v.z*v.z + v.w*v.w;
#pragma unroll
        for (int off = 32; off >= 1; off >>= 1) { s += __shfl_xor(s, off, 64); ss += __shfl_xor(ss, off, 64); }
        float mean = s * (1.0f/256.0f);
        float rstd = rsqrtf(ss * (1.0f/256.0f) - mean*mean + 1e-5f);
        ushort4 o;
        o.x = f2bf((v.x-mean)*rstd*g4.x + b4.x);
        o.y = f2bf((v.y-mean)*rstd*g4.y + b4.y);
        o.z = f2bf((v.z-mean)*rstd*g4.z + b4.z);
        o.w = f2bf((v.w-mean)*rstd*g4.w + b4.w);
        reinterpret_cast<ushort4*>(xb + row*256)[lane] = o;
    }
}

// ---------------- q~ projection (iteration 0): q~ = LN(slots) @ M^T, c = sn.u
__global__ __launch_bounds__(256) void q_proj(
        const float* __restrict__ slots, const u16* __restrict__ Mb,
        const float* __restrict__ uvec,
        const float* __restrict__ gs, const float* __restrict__ bs,
        u16* __restrict__ qb, float* __restrict__ cvec) {
    __shared__ u16 sn[16*264];
    const int b = blockIdx.x;
    const int tid = threadIdx.x, wid = tid >> 6, lane = tid & 63;
    const int l15 = lane & 15, kq = (lane >> 4) * 8;
    for (int rr = wid; rr < 8; rr += 4) {
        float4 v = reinterpret_cast<const float4*>(slots + (size_t)(b*8 + rr)*256)[lane];
        float s = v.x + v.y + v.z + v.w;
        float ss = v.x*v.x + v.y*v.y + v.z*v.z + v.w*v.w;
#pragma unroll
        for (int off = 32; off >= 1; off >>= 1) { s += __shfl_xor(s, off, 64); ss += __shfl_xor(ss, off, 64); }
        float mean = s * (1.f/256.f);
        float rstd = rsqrtf(ss * (1.f/256.f) - mean*mean + 1e-5f);
        float4 g4 = reinterpret_cast<const float4*>(gs)[lane];
        float4 b4 = reinterpret_cast<const float4*>(bs)[lane];
        ushort4 o;
        o.x = f2bf((v.x-mean)*rstd*g4.x + b4.x);
        o.y = f2bf((v.y-mean)*rstd*g4.y + b4.y);
        o.z = f2bf((v.z-mean)*rstd*g4.z + b4.z);
        o.w = f2bf((v.w-mean)*rstd*g4.w + b4.w);
        *reinterpret_cast<ushort4*>(&sn[rr*264 + lane*4]) = o;
    }
    {
        ushort4 z = {0,0,0,0};
        for (int rr = 8 + wid; rr < 16; rr += 4)
            *reinterpret_cast<ushort4*>(&sn[rr*264 + lane*4]) = z;
    }
    __syncthreads();
    {   // c_i = sn_i . u
        int s = tid >> 5, l = tid & 31;
        float p = 0.f;
#pragma unroll
        for (int i = 0; i < 8; i++)
            p += bf2f(sn[s*264 + l*8 + i]) * uvec[l*8 + i];
#pragma unroll
        for (int off = 16; off >= 1; off >>= 1) p += __shfl_xor(p, off, 64);
        if (l == 0) cvec[b*8 + s] = p;
    }
    short8 af[8];
#pragma unroll
    for (int k = 0; k < 8; k++) af[k] = *reinterpret_cast<const short8*>(&sn[l15*264 + k*32 + kq]);
#pragma unroll
    for (int ct = 0; ct < 4; ct++) {
        int o0 = (wid*4 + ct)*16;
        f32x4 a = (f32x4){0.f,0.f,0.f,0.f};
#pragma unroll
        for (int k = 0; k < 8; k++) {
            short8 bw = *reinterpret_cast<const short8*>(&Mb[(size_t)(o0 + l15)*256 + k*32 + kq]);
            a = mfma16(af[k], bw, a);
        }
        if (lane < 32) {
            int sb = (lane >> 4)*4;
#pragma unroll
            for (int r = 0; r < 4; r++)
                qb[(size_t)(b*8 + sb + r)*256 + o0 + l15] = f2bf(a[r]);
        }
    }
}

// ---------------- fused attention: x read ONCE (LDS tile feeds QK and PV) ---
// 512 blocks (b x 8 segs) = exactly 2/CU. Block covers 512 n as 8 tiles of 64.
// Per tile: cooperative double-buffered stage (1 tile ahead) -> QK from LDS
// (each wave: 16-n quarter) -> softmax -> shared P -> PV with waves split by d
// (64 d each) -> acc completes across tiles, direct coalesced stores. Swizzle
// key(r) = (r&7)^((r>>3)&7) on the staged SOURCE chunks (LDS dest linear).
__global__ __launch_bounds__(256) void attn(
        const u16* __restrict__ qt, const u16* __restrict__ xrow,
        const float* __restrict__ cvec,
        float* __restrict__ num_part, float* __restrict__ den_part) {
    __shared__ u16 xt[2][64*256];   // 64 KB double-buffered x tile
    __shared__ u16 pt[16*72];       // shared P tile (8 slots + 8 pad) x 64 n
    __shared__ float dpd[4][8];
    const int b = blockIdx.x >> 3;
    const int seg = blockIdx.x & 7;
    const int tid = threadIdx.x, wid = tid >> 6, lane = tid & 63;
    const int l15 = lane & 15, quad = lane >> 4, kq = quad * 8;
    const int n0 = seg * 512;
    const u16* xsrc = xrow + (size_t)b*4096*256;

    auto STAGE = [&](int t) {
        u16* dst = &xt[t & 1][(wid*16) * 256];
        const u16* src = xsrc + (size_t)(n0 + t*64 + wid*16) * 256;
        const int half = lane >> 5, c = lane & 31;
#pragma unroll
        for (int i = 0; i < 8; i++) {
            const int rl = wid*16 + i*2 + half;           // tile-local row
            const int key = (rl & 7) ^ ((rl >> 3) & 7);
            gload_lds16(src + (size_t)(i*2 + half)*256 + ((c ^ key))*8, dst + i*2*256);
        }
    };

    STAGE(0);                                   // prologue: tile 0 in flight
    {
        ushort4 z4 = {0,0,0,0};
        if (tid < 144)                          // zero P pad rows 8..15
            *reinterpret_cast<ushort4*>(&pt[8*72 + tid*4]) = z4;
    }
    // q~ A-fragment from global, rows >=8 zeroed
    short8 aq[8];
    {
        const u16* qrow = &qt[((size_t)b*8 + (l15 & 7))*256 + kq];
        short8 z = {0,0,0,0,0,0,0,0};
#pragma unroll
        for (int kk = 0; kk < 8; kk++) {
            short8 t = *reinterpret_cast<const short8*>(&qrow[kk*32]);
            aq[kk] = (l15 < 8) ? t : z;
        }
    }
    float cc[4];
#pragma unroll
    for (int r = 0; r < 4; r++) {
        int rowi = quad*4 + r;
        cc[r] = (rowi < 8) ? cvec[b*8 + rowi] : 0.f;
    }
    f32x4 acc[4];
#pragma unroll
    for (int dt = 0; dt < 4; dt++) acc[dt] = (f32x4){0.f,0.f,0.f,0.f};
    float psum[4] = {0.f,0.f,0.f,0.f};

    __syncthreads();    // staging(0) drained (compiler emits vmcnt 0) + pt zero

    for (int t = 0; t < 8; t++) {
        if (t < 7) STAGE(t + 1);                // next tile flies under compute
        const u16* tw = xt[t & 1];
        // ---- QK: wave's 16-n quarter, B-frags from LDS ----
        const int rq = wid*16 + l15;
        const int keyq = (rq & 7) ^ ((rq >> 3) & 7);
        f32x4 dd = (f32x4){0.f,0.f,0.f,0.f};
#pragma unroll
        for (int kk = 0; kk < 8; kk++) {
            short8 bf = *reinterpret_cast<const short8*>(
                &tw[rq*256 + (((kk*4 + quad) ^ keyq))*8]);
            dd = mfma16(aq[kk], bf, dd);
        }
        // ---- softmax over slots for this wave's 16 columns ----
        float t0 = (dd[0] + cc[0])*0.0625f, t1 = (dd[1] + cc[1])*0.0625f;
        float t2 = (dd[2] + cc[2])*0.0625f, t3 = (dd[3] + cc[3])*0.0625f;
        float m4 = fmaxf(fmaxf(t0,t1), fmaxf(t2,t3));
        float m8 = fmaxf(m4, __shfl_xor(m4, 16, 64));
        float e0 = __expf(t0-m8), e1 = __expf(t1-m8), e2 = __expf(t2-m8), e3 = __expf(t3-m8);
        float s4 = e0+e1+e2+e3;
        float s8 = s4 + __shfl_xor(s4, 16, 64);
        float inv = 1.0f / s8;
        u16 h0 = f2bf(e0*inv + 1e-8f);
        u16 h1 = f2bf(e1*inv + 1e-8f);
        u16 h2 = f2bf(e2*inv + 1e-8f);
        u16 h3 = f2bf(e3*inv + 1e-8f);
        if (lane < 32) {
            int sb = quad*4, col = wid*16 + l15;
            pt[(sb+0)*72 + col] = h0;
            pt[(sb+1)*72 + col] = h1;
            pt[(sb+2)*72 + col] = h2;
            pt[(sb+3)*72 + col] = h3;
            psum[0] += bf2f(h0); psum[1] += bf2f(h1);
            psum[2] += bf2f(h2); psum[3] += bf2f(h3);
        }
        __syncthreads();   // P complete (lgkm drained by barrier)
        // ---- PV: wave owns d-range [wid*64, wid*64+64) ----
        short8 ap0 = *reinterpret_cast<const short8*>(&pt[l15*72 + kq]);
        short8 ap1 = *reinterpret_cast<const short8*>(&pt[l15*72 + 32 + kq]);
#pragma unroll
        for (int dt = 0; dt < 4; dt++) {
            const int d = (wid*4 + dt)*16 + l15;
            const int g = d >> 3, e = d & 7;
            short8 pv0, pv1;
#pragma unroll
            for (int j = 0; j < 8; j++) {
                const int ra = quad*8 + j;                 // ks=0 rows 0..31
                const int ka = (ra & 7) ^ ((ra >> 3) & 7);
                pv0[j] = (short)tw[ra*256 + ((g ^ ka))*8 + e];
                const int rb2 = 32 + quad*8 + j;           // ks=1 rows 32..63
                const int kb2 = (rb2 & 7) ^ ((rb2 >> 3) & 7);
                pv1[j] = (short)tw[rb2*256 + ((g ^ kb2))*8 + e];
            }
            acc[dt] = mfma16(ap0, pv0, acc[dt]);
            acc[dt] = mfma16(ap1, pv1, acc[dt]);
        }
        __syncthreads();   // PV reads done: pt reusable, staging(t+1) landed
    }
    // ---- epilogue: den cross-wave reduce; num direct store (complete) ----
#pragma unroll
    for (int off = 1; off < 16; off <<= 1) {
#pragma unroll
        for (int r = 0; r < 4; r++) psum[r] += __shfl_xor(psum[r], off, 64);
    }
    if (quad < 2 && l15 == 0) {
#pragma unroll
        for (int r = 0; r < 4; r++) dpd[wid][quad*4 + r] = psum[r];
    }
    const size_t base = (size_t)(b*8 + seg) * 8;
    if (quad < 2) {
#pragma unroll
        for (int dt = 0; dt < 4; dt++)
#pragma unroll
            for (int rr = 0; rr < 4; rr++)
                num_part[(base + quad*4 + rr)*256 + (wid*4 + dt)*16 + l15] = acc[dt][rr];
    }
    __syncthreads();
    if (tid < 8)
        den_part[base + tid] = dpd[0][tid] + dpd[1][tid] + dpd[2][tid] + dpd[3][tid];
}

// ---------------- per-iteration tail: avg -> Wv -> GRU -> MLP -> slots (+q~)
__global__ __launch_bounds__(768) void finalize(
        const float* __restrict__ slots_in, const float* __restrict__ num_part, const float* __restrict__ den_part,
        const u16* __restrict__ wihb, const float* __restrict__ bih,
        const u16* __restrict__ whhb, const float* __restrict__ bhh,
        const u16* __restrict__ w1b, const float* __restrict__ b1v,
        const u16* __restrict__ w2b, const float* __restrict__ b2v,
        const u16* __restrict__ wvb, const float* __restrict__ bvv,
        const float* __restrict__ gff, const float* __restrict__ bff,
        float* __restrict__ slots_out,
        const u16* __restrict__ Mb, const float* __restrict__ uvec,
        const float* __restrict__ gs, const float* __restrict__ bs,
        u16* __restrict__ qb, float* __restrict__ cvec, int do_q) {
    __shared__ u16 updb[16*264];
    __shared__ u16 prevb[16*264];
    __shared__ u16 lnb[16*264];
    __shared__ float gx[8*776];
    __shared__ float gh[8*776];
    __shared__ float snew[8*256];
    __shared__ float dsum_s[8];
    float* sfin = gx;    // reuse after gates consumed
    const int b = blockIdx.x;
    const int tid = threadIdx.x, wid = tid >> 6, lane = tid & 63;
    const int l15 = lane & 15, kq = (lane >> 4) * 8;
    if (tid < 8) {
        float ds = 0.f;
#pragma unroll
        for (int sg = 0; sg < NSEG; sg++) ds += den_part[(b*NSEG + sg)*8 + tid];
        dsum_s[tid] = ds;
    }
    __syncthreads();
    for (int idx = tid; idx < 2048; idx += 768) {
        int s = idx >> 8, d = idx & 255;
        float ns = 0.f;
#pragma unroll
        for (int sg = 0; sg < NSEG; sg++)
            ns += num_part[((size_t)(b*NSEG + sg)*8 + s)*256 + d];
        updb[s*264 + d] = f2bf(ns / dsum_s[s]);   // avg = attn-weighted x^ mean
        prevb[s*264 + d] = f2bf(slots_in[(size_t)(b*8 + s)*256 + d]);
        updb[(8+s)*264 + d] = 0;
        prevb[(8+s)*264 + d] = 0;
        lnb[(8+s)*264 + d] = 0;
    }
    __syncthreads();
    // updates = avg @ Wv^T + bv  -> lnb rows 0..7
    {
        short8 av[8];
#pragma unroll
        for (int k = 0; k < 8; k++)
            av[k] = *reinterpret_cast<const short8*>(&updb[l15*264 + k*32 + kq]);
        for (int ct = wid; ct < 16; ct += 12) {
            int o0 = ct*16;
            f32x4 a = (f32x4){0.f,0.f,0.f,0.f};
#pragma unroll
            for (int k = 0; k < 8; k++) {
                short8 bw = *reinterpret_cast<const short8*>(&wvb[(size_t)(o0 + l15)*256 + k*32 + kq]);
                a = mfma16(av[k], bw, a);
            }
            if (lane < 32) {
                int sb = (lane >> 4)*4, o = o0 + l15;
                float bb2 = bvv[o];
#pragma unroll
                for (int r = 0; r < 4; r++)
                    lnb[(sb+r)*264 + o] = f2bf(a[r] + bb2);
            }
        }
    }
    __syncthreads();
    short8 au[8], ap[8];
#pragma unroll
    for (int k = 0; k < 8; k++) {
        au[k] = *reinterpret_cast<const short8*>(&lnb[l15*264 + k*32 + kq]);
        ap[k] = *reinterpret_cast<const short8*>(&prevb[l15*264 + k*32 + kq]);
    }
#pragma unroll
    for (int ct = 0; ct < 4; ct++) {
        int o0 = (wid*4 + ct)*16;
        f32x4 ax = (f32x4){0.f,0.f,0.f,0.f}, ah = (f32x4){0.f,0.f,0.f,0.f};
#pragma unroll
        for (int k = 0; k < 8; k++) {
            short8 bx = *reinterpret_cast<const short8*>(&wihb[(size_t)(o0 + l15)*256 + k*32 + kq]);
            short8 bh = *reinterpret_cast<const short8*>(&whhb[(size_t)(o0 + l15)*256 + k*32 + kq]);
            ax = mfma16(au[k], bx, ax);
            ah = mfma16(ap[k], bh, ah);
        }
        if (lane < 32) {
            int sb = (lane >> 4)*4, o = o0 + l15;
            float bxs = bih[o], bhs = bhh[o];
#pragma unroll
            for (int r = 0; r < 4; r++) {
                gx[(sb+r)*776 + o] = ax[r] + bxs;
                gh[(sb+r)*776 + o] = ah[r] + bhs;
            }
        }
    }
    __syncthreads();
    for (int idx = tid; idx < 2048; idx += 768) {
        int s = idx >> 8, j = idx & 255;
        float xr = gx[s*776 + j], xz = gx[s*776 + 256 + j], xn = gx[s*776 + 512 + j];
        float hr = gh[s*776 + j], hz = gh[s*776 + 256 + j], hn = gh[s*776 + 512 + j];
        float r_ = 1.f/(1.f + __expf(-(xr+hr)));
        float z_ = 1.f/(1.f + __expf(-(xz+hz)));
        float n_ = tanhf(xn + r_*hn);
        float pv = slots_in[(size_t)(b*8 + s)*256 + j];
        snew[s*256 + j] = (1.f - z_)*n_ + z_*pv;
    }
    __syncthreads();
    if (wid < 8) {
        int rr = wid;
        float4 v = reinterpret_cast<const float4*>(&snew[rr*256])[lane];
        float s = v.x + v.y + v.z + v.w;
        float ss = v.x*v.x + v.y*v.y + v.z*v.z + v.w*v.w;
#pragma unroll
        for (int off = 32; off >= 1; off >>= 1) { s += __shfl_xor(s, off, 64); ss += __shfl_xor(ss, off, 64); }
        float mean = s * (1.f/256.f);
        float rstd = rsqrtf(ss * (1.f/256.f) - mean*mean + 1e-5f);
        float4 g4 = reinterpret_cast<const float4*>(gff)[lane];
        float4 b4 = reinterpret_cast<const float4*>(bff)[lane];
        ushort4 o;
        o.x = f2bf((v.x-mean)*rstd*g4.x + b4.x);
        o.y = f2bf((v.y-mean)*rstd*g4.y + b4.y);
        o.z = f2bf((v.z-mean)*rstd*g4.z + b4.z);
        o.w = f2bf((v.w-mean)*rstd*g4.w + b4.w);
        *reinterpret_cast<ushort4*>(&lnb[rr*264 + lane*4]) = o;
    } else {
        ushort4 z = {0,0,0,0};
        *reinterpret_cast<ushort4*>(&lnb[wid*264 + lane*4]) = z;
        *reinterpret_cast<ushort4*>(&lnb[(wid+4)*264 + lane*4]) = z;
    }
    __syncthreads();
    short8 al[8];
#pragma unroll
    for (int k = 0; k < 8; k++) al[k] = *reinterpret_cast<const short8*>(&lnb[l15*264 + k*32 + kq]);
    for (int ct = wid; ct < 16; ct += 12) {
        int o0 = ct*16;
        f32x4 a = (f32x4){0.f,0.f,0.f,0.f};
#pragma unroll
        for (int k = 0; k < 8; k++) {
            short8 bw = *reinterpret_cast<const short8*>(&w1b[(size_t)(o0 + l15)*256 + k*32 + kq]);
            a = mfma16(al[k], bw, a);
        }
        if (lane < 32) {
            int sb = (lane >> 4)*4, o = o0 + l15;
            float bb = b1v[o];
#pragma unroll
            for (int r = 0; r < 4; r++)
                updb[(sb+r)*264 + o] = f2bf(fmaxf(a[r] + bb, 0.f));
        }
    }
    __syncthreads();
    short8 ah2[8];
#pragma unroll
    for (int k = 0; k < 8; k++) ah2[k] = *reinterpret_cast<const short8*>(&updb[l15*264 + k*32 + kq]);
    for (int ct = wid; ct < 16; ct += 12) {
        int o0 = ct*16;
        f32x4 a = (f32x4){0.f,0.f,0.f,0.f};
#pragma unroll
        for (int k = 0; k < 8; k++) {
            short8 bw = *reinterpret_cast<const short8*>(&w2b[(size_t)(o0 + l15)*256 + k*32 + kq]);
            a = mfma16(ah2[k], bw, a);
        }
        if (lane < 32) {
            int sb = (lane >> 4)*4, o = o0 + l15;
            float bb = b2v[o];
#pragma unroll
            for (int r = 0; r < 4; r++) {
                float vfin = snew[(sb+r)*256 + o] + a[r] + bb;
                slots_out[(size_t)(b*8 + sb + r)*256 + o] = vfin;
                sfin[(sb+r)*256 + o] = vfin;
            }
        }
    }
    if (!do_q) return;
    __syncthreads();
    // fused q~ projection for next iteration: q~ = LN(slots_new) @ M^T, c = sn.u
    if (wid < 8) {
        int rr = wid;
        float4 v = reinterpret_cast<const float4*>(&sfin[rr*256])[lane];
        float s = v.x + v.y + v.z + v.w;
        float ss = v.x*v.x + v.y*v.y + v.z*v.z + v.w*v.w;
#pragma unroll
        for (int off = 32; off >= 1; off >>= 1) { s += __shfl_xor(s, off, 64); ss += __shfl_xor(ss, off, 64); }
        float mean = s * (1.f/256.f);
        float rstd = rsqrtf(ss * (1.f/256.f) - mean*mean + 1e-5f);
        float4 g4 = reinterpret_cast<const float4*>(gs)[lane];
        float4 b4 = reinterpret_cast<const float4*>(bs)[lane];
        ushort4 o;
        o.x = f2bf((v.x-mean)*rstd*g4.x + b4.x);
        o.y = f2bf((v.y-mean)*rstd*g4.y + b4.y);
        o.z = f2bf((v.z-mean)*rstd*g4.z + b4.z);
        o.w = f2bf((v.w-mean)*rstd*g4.w + b4.w);
        *reinterpret_cast<ushort4*>(&lnb[rr*264 + lane*4]) = o;
    } else {
        ushort4 z = {0,0,0,0};
        *reinterpret_cast<ushort4*>(&lnb[wid*264 + lane*4]) = z;
        *reinterpret_cast<ushort4*>(&lnb[(wid+4)*264 + lane*4]) = z;
    }
    __syncthreads();
    if (tid < 256) {
        int s = tid >> 5, l = tid & 31;
        float p = 0.f;
#pragma unroll
        for (int i = 0; i < 8; i++)
            p += bf2f(lnb[s*264 + l*8 + i]) * uvec[l*8 + i];
#pragma unroll
        for (int off = 16; off >= 1; off >>= 1) p += __shfl_xor(p, off, 64);
        if (l == 0) cvec[b*8 + s] = p;
    }
    short8 alq[8];
#pragma unroll
    for (int k = 0; k < 8; k++) alq[k] = *reinterpret_cast<const short8*>(&lnb[l15*264 + k*32 + kq]);
    for (int ct = wid; ct < 16; ct += 12) {
        int o0 = ct*16;
        f32x4 a = (f32x4){0.f,0.f,0.f,0.f};
#pragma unroll
        for (int k = 0; k < 8; k++) {
            short8 bw = *reinterpret_cast<const short8*>(&Mb[(size_t)(o0 + l15)*256 + k*32 + kq]);
            a = mfma16(alq[k], bw, a);
        }
        if (lane < 32) {
            int sb = (lane >> 4)*4, o = o0 + l15;
#pragma unroll
            for (int r = 0; r < 4; r++)
                qb[(size_t)(b*8 + sb + r)*256 + o] = f2bf(a[r]);
        }
    }
}

extern "C" void kernel_launch(void* const* d_in, const int* in_sizes, int n_in,
                              void* d_out, int out_size, void* d_ws, size_t ws_size,
                              hipStream_t stream) {
    (void)in_sizes; (void)n_in; (void)out_size;
    const float* inputs     = (const float*)d_in[0];
    const float* init_slots = (const float*)d_in[1];
    const float* wq  = (const float*)d_in[2];
    const float* bq  = (const float*)d_in[3];  (void)bq;  // softmax-invariant, dropped
    const float* wk  = (const float*)d_in[4];
    const float* bk  = (const float*)d_in[5];
    const float* wv  = (const float*)d_in[6];
    const float* bv  = (const float*)d_in[7];
    const float* wih = (const float*)d_in[8];
    const float* bih = (const float*)d_in[9];
    const float* whh = (const float*)d_in[10];
    const float* bhh = (const float*)d_in[11];
    const float* w1  = (const float*)d_in[12];
    const float* b1  = (const float*)d_in[13];
    const float* w2  = (const float*)d_in[14];
    const float* b2  = (const float*)d_in[15];
    const float* g_in = (const float*)d_in[16];
    const float* b_in = (const float*)d_in[17];
    const float* g_sl = (const float*)d_in[18];
    const float* b_sl = (const float*)d_in[19];
    const float* g_ff = (const float*)d_in[20];
    const float* b_ff = (const float*)d_in[21];

    char* ws = (char*)d_ws;
    size_t off = 0;
    auto alloc = [&](size_t bytes) -> void* {
        void* p = ws + off;
        off += (bytes + 255) & ~(size_t)255;
        return p;
    };
    u16* xb    = (u16*)alloc((size_t)GROWS * ND * 2);   // LN(x) bf16 [b][n][d]
    u16* qbf   = (u16*)alloc((size_t)NB * NS * ND * 2); // q~ bf16
    float* slots = (float*)alloc((size_t)NB * NS * ND * 4);
    float* nump  = (float*)alloc((size_t)NB * NSEG * NS * ND * 4);
    float* denp  = (float*)alloc((size_t)NB * NSEG * NS * 4);
    float* cvec  = (float*)alloc((size_t)NB * NS * 4);
    float* uvec  = (float*)alloc(256 * 4);
    u16* wvb  = (u16*)alloc(65536 * 2);
    u16* wkTb = (u16*)alloc(65536 * 2);
    u16* wqTb = (u16*)alloc(65536 * 2);
    u16* Mb   = (u16*)alloc(65536 * 2);
    u16* wihb = (u16*)alloc(196608 * 2);
    u16* whhb = (u16*)alloc(196608 * 2);
    u16* w1b  = (u16*)alloc(65536 * 2);
    u16* w2b  = (u16*)alloc(65536 * 2);
    if (off > ws_size) return;  // insufficient workspace -> visible failure

    prep_w<<<2816, 256, 0, stream>>>(wv, wk, wq, wih, whh, w1, w2,
                                     wvb, wkTb, wqTb, wihb, whhb, w1b, w2b);
    prep_M<<<17, 256, 0, stream>>>(wkTb, wqTb, Mb, wq, bk, uvec);
    hipMemcpyAsync(slots, init_slots, (size_t)NB * NS * ND * 4,
                   hipMemcpyDeviceToDevice, stream);
    ln_cast<<<GROWS / 64, 256, 0, stream>>>(inputs, g_in, b_in, xb);
    q_proj<<<NB, 256, 0, stream>>>(slots, Mb, uvec, g_sl, b_sl, qbf, cvec);
    for (int it = 0; it < 3; it++) {
        attn<<<NB * NSEG, 256, 0, stream>>>(qbf, xb, cvec, nump, denp);
        float* outp = (it == 2) ? (float*)d_out : slots;
        finalize<<<NB, 768, 0, stream>>>(slots, nump, denp, wihb, bih, whhb, bhh,
                                         w1b, b1, w2b, b2, wvb, bv, g_ff, b_ff, outp,
                                         Mb, uvec, g_sl, b_sl, qbf, cvec, (it < 2) ? 1 : 0);
    }
}